// Round 15
// baseline (2594.467 us; speedup 1.0000x reference)
//
#include <hip/hip_runtime.h>
#include <cstdint>
#include <cstddef>

#define HCH 192
#define ICH 64
#define NRAD 6
#define SBFD 42

constexpr int NT = 256;

using bfrag = __attribute__((ext_vector_type(8))) short;  // 8 bf16 (4 VGPRs)
using f32x4 = __attribute__((ext_vector_type(4))) float;

#define MFMA16(a, b, c) __builtin_amdgcn_mfma_f32_16x16x32_bf16(a, b, c, 0, 0, 0)

__device__ __forceinline__ float silu_f(float v) {
    return v / (1.0f + __expf(-v));
}

__device__ __forceinline__ unsigned short f2bf(float x) {
    union { float f; unsigned u; } v; v.f = x;
    return (unsigned short)((v.u + 0x7FFFu + ((v.u >> 16) & 1u)) >> 16);
}

__device__ __forceinline__ unsigned f2bf2(float a, float b) {
    return (unsigned)f2bf(a) | ((unsigned)f2bf(b) << 16);
}

__device__ __forceinline__ float bf2f(unsigned short u) {
    union { unsigned u; float f; } v; v.u = ((unsigned)u) << 16;
    return v.f;
}

__device__ __forceinline__ float lo16(unsigned u) {
    union { unsigned x; float f; } v; v.x = u << 16; return v.f;
}
__device__ __forceinline__ float hi16(unsigned u) {
    union { unsigned x; float f; } v; v.x = u & 0xffff0000u; return v.f;
}

__device__ __forceinline__ bfrag pack8(float4 a, float4 b) {
    bfrag r;
    r[0] = (short)f2bf(a.x); r[1] = (short)f2bf(a.y);
    r[2] = (short)f2bf(a.z); r[3] = (short)f2bf(a.w);
    r[4] = (short)f2bf(b.x); r[5] = (short)f2bf(b.y);
    r[6] = (short)f2bf(b.z); r[7] = (short)f2bf(b.w);
    return r;
}

__device__ __forceinline__ bfrag bzero() {
    bfrag r;
    #pragma unroll
    for (int i = 0; i < 8; ++i) r[i] = 0;
    return r;
}

// reg-load a [192][192] bf16 panel (9 uint4/thread, 512 threads)
#define REGLOAD(SRC)                                                             \
    {                                                                            \
        _Pragma("unroll")                                                        \
        for (int it = 0; it < 9; ++it) {                                         \
            int idx = it * 512 + tid;                                            \
            int r = idx / 24, c8 = idx % 24;                                     \
            wr[it] = *(const uint4*)((SRC) + (size_t)r * HCH + c8 * 8);          \
        }                                                                        \
    }
// write the reg-held panel into b_s
#define REGWRITE()                                                               \
    {                                                                            \
        _Pragma("unroll")                                                        \
        for (int it = 0; it < 9; ++it) {                                         \
            int idx = it * 512 + tid;                                            \
            int r = idx / 24, c8 = idx % 24;                                     \
            *(uint4*)&b_s[r][c8 * 8] = wr[it];                                   \
        }                                                                        \
    }
// stage a [192][192] bf16 panel directly (512 threads)
#define STAGE_B(SRC)                                                             \
    {                                                                            \
        _Pragma("unroll")                                                        \
        for (int it = 0; it < 9; ++it) {                                         \
            int idx = it * 512 + tid;                                            \
            int r = idx / 24, c8 = idx % 24;                                     \
            *(uint4*)&b_s[r][c8 * 8] = *(const uint4*)((SRC) + (size_t)r * HCH + c8 * 8); \
        }                                                                        \
    }

// ---------------- weight prep: fp32 [K][N] -> bf16 transposed [N][K] ----------------
#define WSEG 36864
#define WT_DOWN (9 * WSEG)
#define WT_UP   (9 * WSEG + 12288)
#define WT_TOTAL (9 * WSEG + 2 * 12288)

__global__ __launch_bounds__(NT) void prep_k(
    const float* __restrict__ W_kj, const float* __restrict__ W_ji,
    const float* __restrict__ W_lin, const float* __restrict__ resbW,
    const float* __restrict__ resaW, const float* __restrict__ W_down,
    const float* __restrict__ W_up, unsigned short* __restrict__ Wt)
{
    int i = blockIdx.x * NT + threadIdx.x;
    if (i < 9 * WSEG) {
        int seg = i / WSEG, r = i % WSEG;
        int k = r / HCH, n = r % HCH;
        const float* src =
            seg == 0 ? W_kj : seg == 1 ? W_ji : seg == 2 ? W_lin :
            seg <= 4 ? resbW + (seg - 3) * WSEG : resaW + (seg - 5) * WSEG;
        Wt[seg * WSEG + n * HCH + k] = f2bf(src[r]);
    } else if (i < WT_DOWN + 12288) {
        int r = i - WT_DOWN;
        int k = r / ICH, n = r % ICH;           // W_down [192][64]
        Wt[WT_DOWN + n * HCH + k] = f2bf(W_down[r]);
    } else if (i < WT_TOTAL) {
        int r = i - WT_UP;
        int k = r / HCH, n = r % HCH;           // W_up [64][192]
        Wt[WT_UP + n * ICH + k] = f2bf(W_up[r]);
    }
}

// wc_rbf[6,192] = W_rbf1[6,8] @ W_rbf2[8,192]  (kept fp32)
__global__ void wc_k(const float* __restrict__ W_rbf1, const float* __restrict__ W_rbf2,
                     float* __restrict__ wc)
{
    int tid = blockIdx.x * blockDim.x + threadIdx.x;
    if (tid < NRAD * HCH) {
        int r = tid / HCH, c = tid % HCH;
        float a = 0.f;
        #pragma unroll
        for (int b = 0; b < 8; ++b) a += W_rbf1[r * 8 + b] * W_rbf2[b * HCH + c];
        wc[tid] = a;
    }
}

// ---------------- head: x -> x64b; Wt_down prefetched during GEMM1 ----------------
__global__ __launch_bounds__(512) void fused12_k(
    const float* __restrict__ x, const unsigned short* __restrict__ Wt_kj,
    const float* __restrict__ b_kj, const float* __restrict__ rbf,
    const float* __restrict__ wc, const unsigned short* __restrict__ Wt_down,
    unsigned short* __restrict__ x64b, int E)
{
    __shared__ unsigned short b_s[192][200];
    __shared__ unsigned short u_s[128][200];
    __shared__ float wc_s[NRAD * HCH];
    const int tid = threadIdx.x;
    const int lane = tid & 63, w = tid >> 6;
    const int row0 = blockIdx.x * 128;
    const int lr = lane & 15, lq = lane >> 4;
    const int kq = lq * 8;
    const int ra = row0 + w * 16 + lr;
    const bool rav = ra < E;

    STAGE_B(Wt_kj);
    for (int i = tid; i < NRAD * HCH; i += 512) wc_s[i] = wc[i];

    bfrag a[6];
    #pragma unroll
    for (int ks = 0; ks < 6; ++ks) {
        float4 a0 = make_float4(0,0,0,0), a1 = make_float4(0,0,0,0);
        if (rav) {
            a0 = *(const float4*)(x + (size_t)ra * HCH + ks * 32 + kq);
            a1 = *(const float4*)(x + (size_t)ra * HCH + ks * 32 + kq + 4);
        }
        a[ks] = pack8(a0, a1);
    }
    float rb[4][NRAD];
    #pragma unroll
    for (int r = 0; r < 4; ++r) {
        int grow = row0 + w * 16 + lq * 4 + r;
        #pragma unroll
        for (int q = 0; q < NRAD; ++q)
            rb[r][q] = (grow < E) ? rbf[(size_t)grow * NRAD + q] : 0.f;
    }
    __syncthreads();

    // prefetch Wt_down into regs (overlaps GEMM1)
    uint4 wd[3];
    #pragma unroll
    for (int it = 0; it < 3; ++it) {
        int idx = it * 512 + tid;
        int r = idx / 24, c8 = idx % 24;
        wd[it] = *(const uint4*)(Wt_down + (size_t)r * HCH + c8 * 8);
    }

    __builtin_amdgcn_s_setprio(1);
    #pragma unroll
    for (int t = 0; t < 12; ++t) {
        f32x4 acc = (f32x4){0.f, 0.f, 0.f, 0.f};
        #pragma unroll
        for (int ks = 0; ks < 6; ++ks) {
            bfrag b = *(const bfrag*)&b_s[t * 16 + lr][ks * 32 + kq];
            acc = MFMA16(a[ks], b, acc);
        }
        __builtin_amdgcn_s_setprio(0);
        int col = t * 16 + lr;
        float bb = b_kj[col];
        #pragma unroll
        for (int r = 0; r < 4; ++r) {
            float sv = silu_f(acc[r] + bb);
            float rh = 0.f;
            #pragma unroll
            for (int q = 0; q < NRAD; ++q) rh += rb[r][q] * wc_s[q * HCH + col];
            u_s[w * 16 + lq * 4 + r][col] = f2bf(sv * rh);
        }
        __builtin_amdgcn_s_setprio(1);
    }
    __builtin_amdgcn_s_setprio(0);
    __syncthreads();

    #pragma unroll
    for (int it = 0; it < 3; ++it) {
        int idx = it * 512 + tid;
        int r = idx / 24, c8 = idx % 24;
        *(uint4*)&b_s[r][c8 * 8] = wd[it];
    }
    bfrag a2[6];
    #pragma unroll
    for (int ks = 0; ks < 6; ++ks)
        a2[ks] = *(const bfrag*)&u_s[w * 16 + lr][ks * 32 + kq];
    __syncthreads();

    float o[4][4];
    #pragma unroll
    for (int t = 0; t < 4; ++t) {
        f32x4 acc = (f32x4){0.f, 0.f, 0.f, 0.f};
        #pragma unroll
        for (int ks = 0; ks < 6; ++ks) {
            bfrag b = *(const bfrag*)&b_s[t * 16 + lr][ks * 32 + kq];
            acc = MFMA16(a2[ks], b, acc);
        }
        #pragma unroll
        for (int r = 0; r < 4; ++r) o[t][r] = silu_f(acc[r]);
    }
    __syncthreads();
    #pragma unroll
    for (int t = 0; t < 4; ++t)
        #pragma unroll
        for (int r = 0; r < 4; ++r)
            u_s[w * 16 + lq * 4 + r][t * 16 + lr] = f2bf(o[t][r]);
    __syncthreads();

    #pragma unroll
    for (int it = 0; it < 2; ++it) {
        int idx = it * 512 + tid;
        int r = idx >> 3, c8 = (idx & 7) * 8;
        int grow = row0 + r;
        if (grow < E)
            *(uint4*)(x64b + (size_t)grow * ICH + c8) = *(const uint4*)&u_s[r][c8];
    }
}

// ---------------- combine: B staged in LDS (round-12, proven) ----------------
__global__ __launch_bounds__(512) void combine_k(
    const float* __restrict__ x, const unsigned short* __restrict__ Wt_ji,
    const float* __restrict__ b_ji, const unsigned short* __restrict__ aggB,
    const unsigned short* __restrict__ Wt_up, unsigned short* __restrict__ hB, int E)
{
    __shared__ unsigned short b_s[192][200];
    __shared__ unsigned short bu_s[192][72];
    const int tid = threadIdx.x;
    const int lane = tid & 63, w = tid >> 6;
    const int row0 = blockIdx.x * 128;
    const int lr = lane & 15, lq = lane >> 4;
    const int kq = lq * 8;
    const int ra = row0 + w * 16 + lr;
    const bool rav = ra < E;

    STAGE_B(Wt_ji);
    #pragma unroll
    for (int it = 0; it < 3; ++it) {
        int idx = it * 512 + tid;
        int r = idx / 8, c8 = idx % 8;
        *(uint4*)&bu_s[r][c8 * 8] = *(const uint4*)(Wt_up + (size_t)r * ICH + c8 * 8);
    }

    bfrag aag[2], ax[6];
    #pragma unroll
    for (int ks = 0; ks < 2; ++ks)
        aag[ks] = rav ? *(const bfrag*)(aggB + (size_t)ra * ICH + ks * 32 + kq) : bzero();
    #pragma unroll
    for (int ks = 0; ks < 6; ++ks) {
        float4 a0 = make_float4(0,0,0,0), a1 = make_float4(0,0,0,0);
        if (rav) {
            a0 = *(const float4*)(x + (size_t)ra * HCH + ks * 32 + kq);
            a1 = *(const float4*)(x + (size_t)ra * HCH + ks * 32 + kq + 4);
        }
        ax[ks] = pack8(a0, a1);
    }
    __syncthreads();

    __builtin_amdgcn_s_setprio(1);
    #pragma unroll
    for (int t = 0; t < 12; ++t) {
        f32x4 au = (f32x4){0.f, 0.f, 0.f, 0.f};
        #pragma unroll
        for (int ks = 0; ks < 2; ++ks) {
            bfrag bu = *(const bfrag*)&bu_s[t * 16 + lr][ks * 32 + kq];
            au = MFMA16(aag[ks], bu, au);
        }
        f32x4 aj = (f32x4){0.f, 0.f, 0.f, 0.f};
        #pragma unroll
        for (int ks = 0; ks < 6; ++ks) {
            bfrag b = *(const bfrag*)&b_s[t * 16 + lr][ks * 32 + kq];
            aj = MFMA16(ax[ks], b, aj);
        }
        __builtin_amdgcn_s_setprio(0);
        int col = t * 16 + lr;
        float bb = b_ji[col];
        #pragma unroll
        for (int r = 0; r < 4; ++r) {
            int grow = row0 + w * 16 + lq * 4 + r;
            if (grow >= E) continue;
            hB[(size_t)grow * HCH + col] = f2bf(silu_f(aj[r] + bb) + silu_f(au[r]));
        }
        __builtin_amdgcn_s_setprio(1);
    }
    __builtin_amdgcn_s_setprio(0);
}

// ---------------- fused res_b0 + lin: r13 geometry + panel prefetch + setprio ----------------
__global__ __launch_bounds__(512) void reslin_k(
    unsigned short* __restrict__ hB, const unsigned short* __restrict__ Wt0,
    const unsigned short* __restrict__ Wt1, const unsigned short* __restrict__ Wt_lin,
    const float* __restrict__ b0, const float* __restrict__ b1,
    const float* __restrict__ b_lin, const float* __restrict__ x, int E)
{
    __shared__ unsigned short b_s[192][200];   // 76.8 KB
    __shared__ unsigned short t_s[128][200];   // 51.2 KB (wave-private rows)
    const int tid = threadIdx.x;
    const int lane = tid & 63, w = tid >> 6;
    const int row0 = blockIdx.x * 128;
    const int lr = lane & 15, lq = lane >> 4;
    const int kq = lq * 8;
    const int ra = row0 + w * 16 + lr;
    const bool rav = ra < E;

    uint4 wr[9];
    STAGE_B(Wt0);
    bfrag a[6];
    #pragma unroll
    for (int ks = 0; ks < 6; ++ks)
        a[ks] = rav ? *(const bfrag*)(hB + (size_t)ra * HCH + ks * 32 + kq) : bzero();
    __syncthreads();

    REGLOAD(Wt1);   // prefetch W1, hides under GEMM1

    // GEMM1: t = silu(h@W0+b0) -> t_s
    __builtin_amdgcn_s_setprio(1);
    #pragma unroll
    for (int t = 0; t < 12; ++t) {
        f32x4 acc = (f32x4){0.f, 0.f, 0.f, 0.f};
        #pragma unroll
        for (int ks = 0; ks < 6; ++ks) {
            bfrag b = *(const bfrag*)&b_s[t * 16 + lr][ks * 32 + kq];
            acc = MFMA16(a[ks], b, acc);
        }
        __builtin_amdgcn_s_setprio(0);
        int col = t * 16 + lr;
        float bb = b0[col];
        #pragma unroll
        for (int r = 0; r < 4; ++r)
            t_s[w * 16 + lq * 4 + r][col] = f2bf(silu_f(acc[r] + bb));
        __builtin_amdgcn_s_setprio(1);
    }
    __builtin_amdgcn_s_setprio(0);
    __syncthreads();    // all b_s reads done
    REGWRITE();         // W1 -> b_s
    __syncthreads();

    REGLOAD(Wt_lin);    // prefetch W_lin, hides under GEMM2
    bfrag a2[6];
    #pragma unroll
    for (int ks = 0; ks < 6; ++ks)
        a2[ks] = *(const bfrag*)&t_s[w * 16 + lr][ks * 32 + kq];

    // GEMM2: h1 = h + silu(t@W1+b1) -> t_s
    __builtin_amdgcn_s_setprio(1);
    #pragma unroll
    for (int t = 0; t < 12; ++t) {
        f32x4 acc = (f32x4){0.f, 0.f, 0.f, 0.f};
        #pragma unroll
        for (int ks = 0; ks < 6; ++ks) {
            bfrag b = *(const bfrag*)&b_s[t * 16 + lr][ks * 32 + kq];
            acc = MFMA16(a2[ks], b, acc);
        }
        __builtin_amdgcn_s_setprio(0);
        int col = t * 16 + lr;
        float bb = b1[col];
        #pragma unroll
        for (int r = 0; r < 4; ++r) {
            int rloc = w * 16 + lq * 4 + r;
            int grow = row0 + rloc;
            float h1 = 0.f;
            if (grow < E)
                h1 = bf2f(hB[(size_t)grow * HCH + col]) + silu_f(acc[r] + bb);
            t_s[rloc][col] = f2bf(h1);
        }
        __builtin_amdgcn_s_setprio(1);
    }
    __builtin_amdgcn_s_setprio(0);
    __syncthreads();
    REGWRITE();         // W_lin -> b_s
    __syncthreads();

    bfrag a3[6];
    #pragma unroll
    for (int ks = 0; ks < 6; ++ks)
        a3[ks] = *(const bfrag*)&t_s[w * 16 + lr][ks * 32 + kq];

    // GEMM3: hB = bf16( silu(h1@W_lin + b_lin) + x )
    __builtin_amdgcn_s_setprio(1);
    #pragma unroll
    for (int t = 0; t < 12; ++t) {
        f32x4 acc = (f32x4){0.f, 0.f, 0.f, 0.f};
        #pragma unroll
        for (int ks = 0; ks < 6; ++ks) {
            bfrag b = *(const bfrag*)&b_s[t * 16 + lr][ks * 32 + kq];
            acc = MFMA16(a3[ks], b, acc);
        }
        __builtin_amdgcn_s_setprio(0);
        int col = t * 16 + lr;
        float bb = b_lin[col];
        #pragma unroll
        for (int r = 0; r < 4; ++r) {
            int grow = row0 + w * 16 + lq * 4 + r;
            if (grow >= E) continue;
            size_t off = (size_t)grow * HCH + col;
            hB[off] = f2bf(silu_f(acc[r] + bb) + x[off]);
        }
        __builtin_amdgcn_s_setprio(1);
    }
    __builtin_amdgcn_s_setprio(0);
}

// ---------------- fused res_a0 + res_a1: r13 geometry + panel prefetch + setprio ----------------
__global__ __launch_bounds__(512) void resres_k(
    const unsigned short* __restrict__ hB, const unsigned short* __restrict__ Wt,
    const float* __restrict__ bias, float* __restrict__ out, int E)
{
    __shared__ unsigned short b_s[192][200];
    __shared__ unsigned short t_s[128][200];
    const int tid = threadIdx.x;
    const int lane = tid & 63, w = tid >> 6;
    const int row0 = blockIdx.x * 128;
    const int lr = lane & 15, lq = lane >> 4;
    const int kq = lq * 8;
    const int ra = row0 + w * 16 + lr;
    const bool rav = ra < E;

    uint4 wr[9];
    STAGE_B(Wt);                                     // W0
    bfrag a[6];
    #pragma unroll
    for (int ks = 0; ks < 6; ++ks)
        a[ks] = rav ? *(const bfrag*)(hB + (size_t)ra * HCH + ks * 32 + kq) : bzero();
    __syncthreads();

    REGLOAD(Wt + WSEG);   // prefetch W1

    // GEMM1: t1 = silu(h@W0+b0)
    __builtin_amdgcn_s_setprio(1);
    #pragma unroll
    for (int t = 0; t < 12; ++t) {
        f32x4 acc = (f32x4){0.f, 0.f, 0.f, 0.f};
        #pragma unroll
        for (int ks = 0; ks < 6; ++ks) {
            bfrag b = *(const bfrag*)&b_s[t * 16 + lr][ks * 32 + kq];
            acc = MFMA16(a[ks], b, acc);
        }
        __builtin_amdgcn_s_setprio(0);
        int col = t * 16 + lr;
        float bb = bias[col];
        #pragma unroll
        for (int r = 0; r < 4; ++r)
            t_s[w * 16 + lq * 4 + r][col] = f2bf(silu_f(acc[r] + bb));
        __builtin_amdgcn_s_setprio(1);
    }
    __builtin_amdgcn_s_setprio(0);
    __syncthreads();
    REGWRITE();          // W1
    __syncthreads();

    REGLOAD(Wt + 2 * WSEG);   // prefetch W2
    bfrag a2[6];
    #pragma unroll
    for (int ks = 0; ks < 6; ++ks)
        a2[ks] = *(const bfrag*)&t_s[w * 16 + lr][ks * 32 + kq];

    // GEMM2: h1 = h + silu(t1@W1+b1); fp32 in regs AND bf16 -> t_s
    float h1reg[12][4];
    __builtin_amdgcn_s_setprio(1);
    #pragma unroll
    for (int t = 0; t < 12; ++t) {
        f32x4 acc = (f32x4){0.f, 0.f, 0.f, 0.f};
        #pragma unroll
        for (int ks = 0; ks < 6; ++ks) {
            bfrag b = *(const bfrag*)&b_s[t * 16 + lr][ks * 32 + kq];
            acc = MFMA16(a2[ks], b, acc);
        }
        __builtin_amdgcn_s_setprio(0);
        int col = t * 16 + lr;
        float bb = bias[HCH + col];
        #pragma unroll
        for (int r = 0; r < 4; ++r) {
            int rloc = w * 16 + lq * 4 + r;
            int grow = row0 + rloc;
            float h1 = 0.f;
            if (grow < E)
                h1 = bf2f(hB[(size_t)grow * HCH + col]) + silu_f(acc[r] + bb);
            h1reg[t][r] = h1;
            t_s[rloc][col] = f2bf(h1);
        }
        __builtin_amdgcn_s_setprio(1);
    }
    __builtin_amdgcn_s_setprio(0);
    __syncthreads();
    REGWRITE();          // W2
    __syncthreads();

    REGLOAD(Wt + 3 * WSEG);   // prefetch W3
    bfrag a3[6];
    #pragma unroll
    for (int ks = 0; ks < 6; ++ks)
        a3[ks] = *(const bfrag*)&t_s[w * 16 + lr][ks * 32 + kq];

    // GEMM3: t2 = silu(h1@W2+b2) -> t_s
    __builtin_amdgcn_s_setprio(1);
    #pragma unroll
    for (int t = 0; t < 12; ++t) {
        f32x4 acc = (f32x4){0.f, 0.f, 0.f, 0.f};
        #pragma unroll
        for (int ks = 0; ks < 6; ++ks) {
            bfrag b = *(const bfrag*)&b_s[t * 16 + lr][ks * 32 + kq];
            acc = MFMA16(a3[ks], b, acc);
        }
        __builtin_amdgcn_s_setprio(0);
        int col = t * 16 + lr;
        float bb = bias[2 * HCH + col];
        #pragma unroll
        for (int r = 0; r < 4; ++r)
            t_s[w * 16 + lq * 4 + r][col] = f2bf(silu_f(acc[r] + bb));
        __builtin_amdgcn_s_setprio(1);
    }
    __builtin_amdgcn_s_setprio(0);
    __syncthreads();
    REGWRITE();          // W3
    __syncthreads();

    bfrag a4[6];
    #pragma unroll
    for (int ks = 0; ks < 6; ++ks)
        a4[ks] = *(const bfrag*)&t_s[w * 16 + lr][ks * 32 + kq];

    // GEMM4: out = h1 + silu(t2@W3+b3)   (fp32 out, fp32 h1 from regs)
    __builtin_amdgcn_s_setprio(1);
    #pragma unroll
    for (int t = 0; t < 12; ++t) {
        f32x4 acc = (f32x4){0.f, 0.f, 0.f, 0.f};
        #pragma unroll
        for (int ks = 0; ks < 6; ++ks) {
            bfrag b = *(const bfrag*)&b_s[t * 16 + lr][ks * 32 + kq];
            acc = MFMA16(a4[ks], b, acc);
        }
        __builtin_amdgcn_s_setprio(0);
        int col = t * 16 + lr;
        float bb = bias[3 * HCH + col];
        #pragma unroll
        for (int r = 0; r < 4; ++r) {
            int grow = row0 + w * 16 + lq * 4 + r;
            if (grow >= E) continue;
            out[(size_t)grow * HCH + col] = h1reg[t][r] + silu_f(acc[r] + bb);
        }
        __builtin_amdgcn_s_setprio(1);
    }
    __builtin_amdgcn_s_setprio(0);
}

// ---------------- CSR scatter->gather pipeline (round-13, proven) ----------------
__global__ __launch_bounds__(256) void pcount_k(
    const float* __restrict__ sbf, const int* __restrict__ idx_ji,
    const float* __restrict__ w1, unsigned short* __restrict__ pB,
    int* __restrict__ counts, int T)
{
    int t = blockIdx.x * 256 + threadIdx.x;
    if (t >= T) return;
    const float* sp = sbf + (size_t)t * SBFD;
    float acc[8];
    #pragma unroll
    for (int b = 0; b < 8; ++b) acc[b] = 0.f;
    #pragma unroll
    for (int r = 0; r < 40; r += 4) {
        float4 v = *(const float4*)(sp + r);
        #pragma unroll
        for (int b = 0; b < 8; ++b)
            acc[b] += v.x * w1[r * 8 + b] + v.y * w1[(r + 1) * 8 + b]
                    + v.z * w1[(r + 2) * 8 + b] + v.w * w1[(r + 3) * 8 + b];
    }
    {
        float2 v = *(const float2*)(sp + 40);
        #pragma unroll
        for (int b = 0; b < 8; ++b)
            acc[b] += v.x * w1[40 * 8 + b] + v.y * w1[41 * 8 + b];
    }
    uint4 pk;
    pk.x = f2bf2(acc[0], acc[1]);
    pk.y = f2bf2(acc[2], acc[3]);
    pk.z = f2bf2(acc[4], acc[5]);
    pk.w = f2bf2(acc[6], acc[7]);
    *(uint4*)(pB + (size_t)t * 8) = pk;
    atomicAdd(&counts[idx_ji[t]], 1);
}

__global__ __launch_bounds__(256) void psum1_k(const int* __restrict__ counts,
                                               int* __restrict__ bsum, int E) {
    __shared__ int s[256];
    int base = blockIdx.x * 1024;
    int tid = threadIdx.x;
    int sum = 0;
    #pragma unroll
    for (int j = 0; j < 4; ++j) { int i = base + j * 256 + tid; if (i < E) sum += counts[i]; }
    s[tid] = sum; __syncthreads();
    for (int off = 128; off > 0; off >>= 1) {
        if (tid < off) s[tid] += s[tid + off];
        __syncthreads();
    }
    if (tid == 0) bsum[blockIdx.x] = s[0];
}

__global__ __launch_bounds__(512) void psum2_k(int* bsum, int G) {
    __shared__ int s[512];
    int tid = threadIdx.x;
    s[tid] = (tid < G) ? bsum[tid] : 0;
    for (int off = 1; off < 512; off <<= 1) {
        __syncthreads();
        int v = (tid >= off) ? s[tid - off] : 0;
        __syncthreads();
        s[tid] += v;
    }
    __syncthreads();
    if (tid < G) bsum[tid] = (tid == 0) ? 0 : s[tid - 1];
}

__global__ __launch_bounds__(256) void psum3_k(const int* __restrict__ counts,
                                               const int* __restrict__ bsum,
                                               int* __restrict__ start, int E) {
    __shared__ int s[256];
    int tid = threadIdx.x;
    int base = blockIdx.x * 1024 + tid * 4;
    int v[4]; int loc = 0;
    #pragma unroll
    for (int j = 0; j < 4; ++j) { v[j] = (base + j < E) ? counts[base + j] : 0; loc += v[j]; }
    s[tid] = loc;
    for (int off = 1; off < 256; off <<= 1) {
        __syncthreads();
        int t2 = (tid >= off) ? s[tid - off] : 0;
        __syncthreads();
        s[tid] += t2;
    }
    __syncthreads();
    int run = bsum[blockIdx.x] + s[tid] - loc;
    #pragma unroll
    for (int j = 0; j < 4; ++j) { if (base + j < E) start[base + j] = run; run += v[j]; }
}

// fill: materialize kj and p streams in bucket order
__global__ __launch_bounds__(256) void fill_k(
    const int* __restrict__ idx_ji, const int* __restrict__ idx_kj,
    const unsigned short* __restrict__ pB, int* __restrict__ start,
    int* __restrict__ kjs, unsigned short* __restrict__ pSort, int T)
{
    int t = blockIdx.x * 256 + threadIdx.x;
    if (t >= T) return;
    int pos = atomicAdd(&start[idx_ji[t]], 1);
    kjs[pos] = idx_kj[t];
    *(uint4*)(pSort + (size_t)pos * 8) = *(const uint4*)(pB + (size_t)t * 8);
}

// gather: sequential kjs/pSort streams; only x64b row-gather is random (L3-hot)
__global__ __launch_bounds__(256) void gather_k(
    const int* __restrict__ kjs, const unsigned short* __restrict__ pSort,
    const unsigned short* __restrict__ x64b, const int* __restrict__ start,
    const int* __restrict__ counts, const float* __restrict__ w2,
    unsigned short* __restrict__ aggB, int E)
{
    int tid = threadIdx.x;
    int wave = (blockIdx.x * 256 + tid) >> 6;
    int lane = tid & 63;
    if (wave >= E) return;

    float wcol[8];
    #pragma unroll
    for (int b = 0; b < 8; ++b) wcol[b] = w2[b * 64 + lane];

    int n = counts[wave];
    int end = start[wave];
    int i = end - n;

    float acc = 0.f;
    for (; i + 4 <= end; i += 4) {
        int k0 = kjs[i], k1 = kjs[i + 1], k2 = kjs[i + 2], k3 = kjs[i + 3];
        uint4 q0 = *(const uint4*)(pSort + (size_t)i * 8);
        uint4 q1 = *(const uint4*)(pSort + (size_t)(i + 1) * 8);
        uint4 q2 = *(const uint4*)(pSort + (size_t)(i + 2) * 8);
        uint4 q3 = *(const uint4*)(pSort + (size_t)(i + 3) * 8);
        float x0 = bf2f(x64b[(size_t)k0 * ICH + lane]);
        float x1 = bf2f(x64b[(size_t)k1 * ICH + lane]);
        float x2 = bf2f(x64b[(size_t)k2 * ICH + lane]);
        float x3 = bf2f(x64b[(size_t)k3 * ICH + lane]);
        float s0 = lo16(q0.x)*wcol[0] + hi16(q0.x)*wcol[1] + lo16(q0.y)*wcol[2] + hi16(q0.y)*wcol[3]
                 + lo16(q0.z)*wcol[4] + hi16(q0.z)*wcol[5] + lo16(q0.w)*wcol[6] + hi16(q0.w)*wcol[7];
        float s1 = lo16(q1.x)*wcol[0] + hi16(q1.x)*wcol[1] + lo16(q1.y)*wcol[2] + hi16(q1.y)*wcol[3]
                 + lo16(q1.z)*wcol[4] + hi16(q1.z)*wcol[5] + lo16(q1.w)*wcol[6] + hi16(q1.w)*wcol[7];
        float s2 = lo16(q2.x)*wcol[0] + hi16(q2.x)*wcol[1] + lo16(q2.y)*wcol[2] + hi16(q2.y)*wcol[3]
                 + lo16(q2.z)*wcol[4] + hi16(q2.z)*wcol[5] + lo16(q2.w)*wcol[6] + hi16(q2.w)*wcol[7];
        float s3 = lo16(q3.x)*wcol[0] + hi16(q3.x)*wcol[1] + lo16(q3.y)*wcol[2] + hi16(q3.y)*wcol[3]
                 + lo16(q3.z)*wcol[4] + hi16(q3.z)*wcol[5] + lo16(q3.w)*wcol[6] + hi16(q3.w)*wcol[7];
        acc += s0 * x0 + s1 * x1 + s2 * x2 + s3 * x3;
    }
    for (; i < end; ++i) {
        int kj = kjs[i];
        uint4 q = *(const uint4*)(pSort + (size_t)i * 8);
        float xv = bf2f(x64b[(size_t)kj * ICH + lane]);
        float sc = lo16(q.x)*wcol[0] + hi16(q.x)*wcol[1] + lo16(q.y)*wcol[2] + hi16(q.y)*wcol[3]
                 + lo16(q.z)*wcol[4] + hi16(q.z)*wcol[5] + lo16(q.w)*wcol[6] + hi16(q.w)*wcol[7];
        acc += sc * xv;
    }
    aggB[(size_t)wave * ICH + lane] = f2bf(acc);
}

extern "C" void kernel_launch(void* const* d_in, const int* in_sizes, int n_in,
                              void* d_out, int out_size, void* d_ws, size_t ws_size,
                              hipStream_t stream) {
    const float* x      = (const float*)d_in[0];
    const float* rbf    = (const float*)d_in[1];
    const float* sbf    = (const float*)d_in[2];
    const int*   idx_kj = (const int*)d_in[3];
    const int*   idx_ji = (const int*)d_in[4];
    const float* W_rbf1 = (const float*)d_in[5];
    const float* W_rbf2 = (const float*)d_in[6];
    const float* W_sbf1 = (const float*)d_in[7];
    const float* W_sbf2 = (const float*)d_in[8];
    const float* W_kj   = (const float*)d_in[9];
    const float* b_kj   = (const float*)d_in[10];
    const float* W_ji   = (const float*)d_in[11];
    const float* b_ji   = (const float*)d_in[12];
    const float* W_down = (const float*)d_in[13];
    const float* W_up   = (const float*)d_in[14];
    const float* resbW  = (const float*)d_in[15];
    const float* resbB  = (const float*)d_in[16];
    const float* W_lin  = (const float*)d_in[17];
    const float* b_lin  = (const float*)d_in[18];
    const float* resaW  = (const float*)d_in[19];
    const float* resaB  = (const float*)d_in[20];

    const int E = in_sizes[0] / HCH;
    const int T = in_sizes[3];
    float* out = (float*)d_out;

    // ws: wc_rbf f32[1152] | counts[E] | start[E] | bsum[512] | kjs[T] |
    //     pB u16[T*8] | pSort u16[T*8] | x64b u16[E*64] | aggB u16[E*64] |
    //     hB u16[E*192] | Wt u16[WT_TOTAL]
    float* wc_rbf = (float*)d_ws;
    int*   counts = (int*)(wc_rbf + NRAD * HCH);
    int*   start  = counts + E;
    int*   bsum   = start + E;
    int*   kjs    = bsum + 512;
    unsigned short* pB    = (unsigned short*)(kjs + T);
    unsigned short* pSort = pB + (size_t)T * 8;
    unsigned short* x64b  = pSort + (size_t)T * 8;
    unsigned short* aggB  = x64b + (size_t)E * ICH;
    unsigned short* hB    = aggB + (size_t)E * ICH;
    unsigned short* Wt    = hB + (size_t)E * HCH;

    const unsigned short* Wt_kj   = Wt;
    const unsigned short* Wt_ji   = Wt + 1 * WSEG;
    const unsigned short* Wt_lin  = Wt + 2 * WSEG;
    const unsigned short* Wt_rb0  = Wt + 3 * WSEG;   // W0, W1 at +WSEG
    const unsigned short* Wt_ra   = Wt + 5 * WSEG;   // ra0_0, ra0_1, ra1_0, ra1_1
    const unsigned short* Wt_down = Wt + WT_DOWN;
    const unsigned short* Wt_up   = Wt + WT_UP;

    const int gb128 = (E + 127) / 128;
    const int gt = (T + 255) / 256;
    const int gscan = (E + 1023) / 1024;

    wc_k<<<(NRAD * HCH + NT - 1) / NT, NT, 0, stream>>>(W_rbf1, W_rbf2, wc_rbf);
    prep_k<<<(WT_TOTAL + NT - 1) / NT, NT, 0, stream>>>(W_kj, W_ji, W_lin, resbW, resaW,
                                                        W_down, W_up, Wt);

    // CSR build + stream materialization
    hipMemsetAsync(counts, 0, (size_t)E * sizeof(int), stream);
    pcount_k<<<gt, 256, 0, stream>>>(sbf, idx_ji, W_sbf1, pB, counts, T);
    psum1_k<<<gscan, 256, 0, stream>>>(counts, bsum, E);
    psum2_k<<<1, 512, 0, stream>>>(bsum, gscan);
    psum3_k<<<gscan, 256, 0, stream>>>(counts, bsum, start, E);
    fill_k<<<gt, 256, 0, stream>>>(idx_ji, idx_kj, pB, start, kjs, pSort, T);

    // x -> x64b (bf16), B via LDS + prefetch
    fused12_k<<<gb128, 512, 0, stream>>>(x, Wt_kj, b_kj, rbf, wc_rbf, Wt_down, x64b, E);
    // aggB = segment_sum(x64b[kjs] * (pSort@W_sbf2))
    gather_k<<<(E + 3) / 4, 256, 0, stream>>>(kjs, pSort, x64b, start, counts, W_sbf2, aggB, E);
    // hB = silu(x@W_ji+b) + silu(agg@W_up), B via LDS
    combine_k<<<gb128, 512, 0, stream>>>(x, Wt_ji, b_ji, aggB, Wt_up, hB, E);
    // res_before + lin fused (prefetch + setprio)
    reslin_k<<<gb128, 512, 0, stream>>>(hB, Wt_rb0, Wt_rb0 + WSEG, Wt_lin,
                                        resbB, resbB + HCH, b_lin, x, E);
    // res_after x2 fused (prefetch + setprio), fp32 out
    resres_k<<<gb128, 512, 0, stream>>>(hB, Wt_ra, resaB, out, E);
}

// Round 16
// 2589.087 us; speedup vs baseline: 1.0021x; 1.0021x over previous
//
#include <hip/hip_runtime.h>
#include <cstdint>
#include <cstddef>

#define HCH 192
#define ICH 64
#define NRAD 6
#define SBFD 42

constexpr int NT = 256;

using bfrag = __attribute__((ext_vector_type(8))) short;  // 8 bf16 (4 VGPRs)
using f32x4 = __attribute__((ext_vector_type(4))) float;

#define MFMA16(a, b, c) __builtin_amdgcn_mfma_f32_16x16x32_bf16(a, b, c, 0, 0, 0)

__device__ __forceinline__ float silu_f(float v) {
    return v / (1.0f + __expf(-v));
}

__device__ __forceinline__ unsigned short f2bf(float x) {
    union { float f; unsigned u; } v; v.f = x;
    return (unsigned short)((v.u + 0x7FFFu + ((v.u >> 16) & 1u)) >> 16);
}

__device__ __forceinline__ unsigned f2bf2(float a, float b) {
    return (unsigned)f2bf(a) | ((unsigned)f2bf(b) << 16);
}

__device__ __forceinline__ float bf2f(unsigned short u) {
    union { unsigned u; float f; } v; v.u = ((unsigned)u) << 16;
    return v.f;
}

__device__ __forceinline__ float lo16(unsigned u) {
    union { unsigned x; float f; } v; v.x = u << 16; return v.f;
}
__device__ __forceinline__ float hi16(unsigned u) {
    union { unsigned x; float f; } v; v.x = u & 0xffff0000u; return v.f;
}

__device__ __forceinline__ bfrag pack8(float4 a, float4 b) {
    bfrag r;
    r[0] = (short)f2bf(a.x); r[1] = (short)f2bf(a.y);
    r[2] = (short)f2bf(a.z); r[3] = (short)f2bf(a.w);
    r[4] = (short)f2bf(b.x); r[5] = (short)f2bf(b.y);
    r[6] = (short)f2bf(b.z); r[7] = (short)f2bf(b.w);
    return r;
}

__device__ __forceinline__ bfrag bzero() {
    bfrag r;
    #pragma unroll
    for (int i = 0; i < 8; ++i) r[i] = 0;
    return r;
}

// reg-load a [192][192] bf16 panel (9 uint4/thread, 512 threads)
#define REGLOAD(SRC)                                                             \
    {                                                                            \
        _Pragma("unroll")                                                        \
        for (int it = 0; it < 9; ++it) {                                         \
            int idx = it * 512 + tid;                                            \
            int r = idx / 24, c8 = idx % 24;                                     \
            wr[it] = *(const uint4*)((SRC) + (size_t)r * HCH + c8 * 8);          \
        }                                                                        \
    }
// write the reg-held panel into b_s
#define REGWRITE()                                                               \
    {                                                                            \
        _Pragma("unroll")                                                        \
        for (int it = 0; it < 9; ++it) {                                         \
            int idx = it * 512 + tid;                                            \
            int r = idx / 24, c8 = idx % 24;                                     \
            *(uint4*)&b_s[r][c8 * 8] = wr[it];                                   \
        }                                                                        \
    }
// stage a [192][192] bf16 panel directly (512 threads)
#define STAGE_B(SRC)                                                             \
    {                                                                            \
        _Pragma("unroll")                                                        \
        for (int it = 0; it < 9; ++it) {                                         \
            int idx = it * 512 + tid;                                            \
            int r = idx / 24, c8 = idx % 24;                                     \
            *(uint4*)&b_s[r][c8 * 8] = *(const uint4*)((SRC) + (size_t)r * HCH + c8 * 8); \
        }                                                                        \
    }

// ---------------- weight prep: fp32 [K][N] -> bf16 transposed [N][K] ----------------
#define WSEG 36864
#define WT_DOWN (9 * WSEG)
#define WT_UP   (9 * WSEG + 12288)
#define WT_TOTAL (9 * WSEG + 2 * 12288)

__global__ __launch_bounds__(NT) void prep_k(
    const float* __restrict__ W_kj, const float* __restrict__ W_ji,
    const float* __restrict__ W_lin, const float* __restrict__ resbW,
    const float* __restrict__ resaW, const float* __restrict__ W_down,
    const float* __restrict__ W_up, unsigned short* __restrict__ Wt)
{
    int i = blockIdx.x * NT + threadIdx.x;
    if (i < 9 * WSEG) {
        int seg = i / WSEG, r = i % WSEG;
        int k = r / HCH, n = r % HCH;
        const float* src =
            seg == 0 ? W_kj : seg == 1 ? W_ji : seg == 2 ? W_lin :
            seg <= 4 ? resbW + (seg - 3) * WSEG : resaW + (seg - 5) * WSEG;
        Wt[seg * WSEG + n * HCH + k] = f2bf(src[r]);
    } else if (i < WT_DOWN + 12288) {
        int r = i - WT_DOWN;
        int k = r / ICH, n = r % ICH;           // W_down [192][64]
        Wt[WT_DOWN + n * HCH + k] = f2bf(W_down[r]);
    } else if (i < WT_TOTAL) {
        int r = i - WT_UP;
        int k = r / HCH, n = r % HCH;           // W_up [64][192]
        Wt[WT_UP + n * ICH + k] = f2bf(W_up[r]);
    }
}

// wc_rbf[6,192] = W_rbf1[6,8] @ W_rbf2[8,192]  (kept fp32)
__global__ void wc_k(const float* __restrict__ W_rbf1, const float* __restrict__ W_rbf2,
                     float* __restrict__ wc)
{
    int tid = blockIdx.x * blockDim.x + threadIdx.x;
    if (tid < NRAD * HCH) {
        int r = tid / HCH, c = tid % HCH;
        float a = 0.f;
        #pragma unroll
        for (int b = 0; b < 8; ++b) a += W_rbf1[r * 8 + b] * W_rbf2[b * HCH + c];
        wc[tid] = a;
    }
}

// ---------------- head: x -> x64b; Wt_down prefetched during GEMM1 ----------------
__global__ __launch_bounds__(512, 2) void fused12_k(
    const float* __restrict__ x, const unsigned short* __restrict__ Wt_kj,
    const float* __restrict__ b_kj, const float* __restrict__ rbf,
    const float* __restrict__ wc, const unsigned short* __restrict__ Wt_down,
    unsigned short* __restrict__ x64b, int E)
{
    __shared__ unsigned short b_s[192][200];
    __shared__ unsigned short u_s[128][200];
    __shared__ float wc_s[NRAD * HCH];
    const int tid = threadIdx.x;
    const int lane = tid & 63, w = tid >> 6;
    const int row0 = blockIdx.x * 128;
    const int lr = lane & 15, lq = lane >> 4;
    const int kq = lq * 8;
    const int ra = row0 + w * 16 + lr;
    const bool rav = ra < E;

    STAGE_B(Wt_kj);
    for (int i = tid; i < NRAD * HCH; i += 512) wc_s[i] = wc[i];

    bfrag a[6];
    #pragma unroll
    for (int ks = 0; ks < 6; ++ks) {
        float4 a0 = make_float4(0,0,0,0), a1 = make_float4(0,0,0,0);
        if (rav) {
            a0 = *(const float4*)(x + (size_t)ra * HCH + ks * 32 + kq);
            a1 = *(const float4*)(x + (size_t)ra * HCH + ks * 32 + kq + 4);
        }
        a[ks] = pack8(a0, a1);
    }
    float rb[4][NRAD];
    #pragma unroll
    for (int r = 0; r < 4; ++r) {
        int grow = row0 + w * 16 + lq * 4 + r;
        #pragma unroll
        for (int q = 0; q < NRAD; ++q)
            rb[r][q] = (grow < E) ? rbf[(size_t)grow * NRAD + q] : 0.f;
    }
    __syncthreads();

    // prefetch Wt_down into regs (overlaps GEMM1)
    uint4 wd[3];
    #pragma unroll
    for (int it = 0; it < 3; ++it) {
        int idx = it * 512 + tid;
        int r = idx / 24, c8 = idx % 24;
        wd[it] = *(const uint4*)(Wt_down + (size_t)r * HCH + c8 * 8);
    }

    __builtin_amdgcn_s_setprio(1);
    #pragma unroll
    for (int t = 0; t < 12; ++t) {
        f32x4 acc = (f32x4){0.f, 0.f, 0.f, 0.f};
        #pragma unroll
        for (int ks = 0; ks < 6; ++ks) {
            bfrag b = *(const bfrag*)&b_s[t * 16 + lr][ks * 32 + kq];
            acc = MFMA16(a[ks], b, acc);
        }
        __builtin_amdgcn_s_setprio(0);
        int col = t * 16 + lr;
        float bb = b_kj[col];
        #pragma unroll
        for (int r = 0; r < 4; ++r) {
            float sv = silu_f(acc[r] + bb);
            float rh = 0.f;
            #pragma unroll
            for (int q = 0; q < NRAD; ++q) rh += rb[r][q] * wc_s[q * HCH + col];
            u_s[w * 16 + lq * 4 + r][col] = f2bf(sv * rh);
        }
        __builtin_amdgcn_s_setprio(1);
    }
    __builtin_amdgcn_s_setprio(0);
    __syncthreads();

    #pragma unroll
    for (int it = 0; it < 3; ++it) {
        int idx = it * 512 + tid;
        int r = idx / 24, c8 = idx % 24;
        *(uint4*)&b_s[r][c8 * 8] = wd[it];
    }
    bfrag a2[6];
    #pragma unroll
    for (int ks = 0; ks < 6; ++ks)
        a2[ks] = *(const bfrag*)&u_s[w * 16 + lr][ks * 32 + kq];
    __syncthreads();

    float o[4][4];
    #pragma unroll
    for (int t = 0; t < 4; ++t) {
        f32x4 acc = (f32x4){0.f, 0.f, 0.f, 0.f};
        #pragma unroll
        for (int ks = 0; ks < 6; ++ks) {
            bfrag b = *(const bfrag*)&b_s[t * 16 + lr][ks * 32 + kq];
            acc = MFMA16(a2[ks], b, acc);
        }
        #pragma unroll
        for (int r = 0; r < 4; ++r) o[t][r] = silu_f(acc[r]);
    }
    __syncthreads();
    #pragma unroll
    for (int t = 0; t < 4; ++t)
        #pragma unroll
        for (int r = 0; r < 4; ++r)
            u_s[w * 16 + lq * 4 + r][t * 16 + lr] = f2bf(o[t][r]);
    __syncthreads();

    #pragma unroll
    for (int it = 0; it < 2; ++it) {
        int idx = it * 512 + tid;
        int r = idx >> 3, c8 = (idx & 7) * 8;
        int grow = row0 + r;
        if (grow < E)
            *(uint4*)(x64b + (size_t)grow * ICH + c8) = *(const uint4*)&u_s[r][c8];
    }
}

// ---------------- combine: B staged in LDS ----------------
__global__ __launch_bounds__(512, 2) void combine_k(
    const float* __restrict__ x, const unsigned short* __restrict__ Wt_ji,
    const float* __restrict__ b_ji, const unsigned short* __restrict__ aggB,
    const unsigned short* __restrict__ Wt_up, unsigned short* __restrict__ hB, int E)
{
    __shared__ unsigned short b_s[192][200];
    __shared__ unsigned short bu_s[192][72];
    const int tid = threadIdx.x;
    const int lane = tid & 63, w = tid >> 6;
    const int row0 = blockIdx.x * 128;
    const int lr = lane & 15, lq = lane >> 4;
    const int kq = lq * 8;
    const int ra = row0 + w * 16 + lr;
    const bool rav = ra < E;

    STAGE_B(Wt_ji);
    #pragma unroll
    for (int it = 0; it < 3; ++it) {
        int idx = it * 512 + tid;
        int r = idx / 8, c8 = idx % 8;
        *(uint4*)&bu_s[r][c8 * 8] = *(const uint4*)(Wt_up + (size_t)r * ICH + c8 * 8);
    }

    bfrag aag[2], ax[6];
    #pragma unroll
    for (int ks = 0; ks < 2; ++ks)
        aag[ks] = rav ? *(const bfrag*)(aggB + (size_t)ra * ICH + ks * 32 + kq) : bzero();
    #pragma unroll
    for (int ks = 0; ks < 6; ++ks) {
        float4 a0 = make_float4(0,0,0,0), a1 = make_float4(0,0,0,0);
        if (rav) {
            a0 = *(const float4*)(x + (size_t)ra * HCH + ks * 32 + kq);
            a1 = *(const float4*)(x + (size_t)ra * HCH + ks * 32 + kq + 4);
        }
        ax[ks] = pack8(a0, a1);
    }
    __syncthreads();

    __builtin_amdgcn_s_setprio(1);
    #pragma unroll
    for (int t = 0; t < 12; ++t) {
        f32x4 au = (f32x4){0.f, 0.f, 0.f, 0.f};
        #pragma unroll
        for (int ks = 0; ks < 2; ++ks) {
            bfrag bu = *(const bfrag*)&bu_s[t * 16 + lr][ks * 32 + kq];
            au = MFMA16(aag[ks], bu, au);
        }
        f32x4 aj = (f32x4){0.f, 0.f, 0.f, 0.f};
        #pragma unroll
        for (int ks = 0; ks < 6; ++ks) {
            bfrag b = *(const bfrag*)&b_s[t * 16 + lr][ks * 32 + kq];
            aj = MFMA16(ax[ks], b, aj);
        }
        __builtin_amdgcn_s_setprio(0);
        int col = t * 16 + lr;
        float bb = b_ji[col];
        #pragma unroll
        for (int r = 0; r < 4; ++r) {
            int grow = row0 + w * 16 + lq * 4 + r;
            if (grow >= E) continue;
            hB[(size_t)grow * HCH + col] = f2bf(silu_f(aj[r] + bb) + silu_f(au[r]));
        }
        __builtin_amdgcn_s_setprio(1);
    }
    __builtin_amdgcn_s_setprio(0);
}

// ---------------- fused res_b0 + lin: prefetch + setprio, VGPR cap lifted ----------------
__global__ __launch_bounds__(512, 2) void reslin_k(
    unsigned short* __restrict__ hB, const unsigned short* __restrict__ Wt0,
    const unsigned short* __restrict__ Wt1, const unsigned short* __restrict__ Wt_lin,
    const float* __restrict__ b0, const float* __restrict__ b1,
    const float* __restrict__ b_lin, const float* __restrict__ x, int E)
{
    __shared__ unsigned short b_s[192][200];   // 76.8 KB
    __shared__ unsigned short t_s[128][200];   // 51.2 KB (wave-private rows)
    const int tid = threadIdx.x;
    const int lane = tid & 63, w = tid >> 6;
    const int row0 = blockIdx.x * 128;
    const int lr = lane & 15, lq = lane >> 4;
    const int kq = lq * 8;
    const int ra = row0 + w * 16 + lr;
    const bool rav = ra < E;

    uint4 wr[9];
    STAGE_B(Wt0);
    bfrag a[6];
    #pragma unroll
    for (int ks = 0; ks < 6; ++ks)
        a[ks] = rav ? *(const bfrag*)(hB + (size_t)ra * HCH + ks * 32 + kq) : bzero();
    __syncthreads();

    REGLOAD(Wt1);   // prefetch W1, hides under GEMM1

    // GEMM1: t = silu(h@W0+b0) -> t_s
    __builtin_amdgcn_s_setprio(1);
    #pragma unroll
    for (int t = 0; t < 12; ++t) {
        f32x4 acc = (f32x4){0.f, 0.f, 0.f, 0.f};
        #pragma unroll
        for (int ks = 0; ks < 6; ++ks) {
            bfrag b = *(const bfrag*)&b_s[t * 16 + lr][ks * 32 + kq];
            acc = MFMA16(a[ks], b, acc);
        }
        __builtin_amdgcn_s_setprio(0);
        int col = t * 16 + lr;
        float bb = b0[col];
        #pragma unroll
        for (int r = 0; r < 4; ++r)
            t_s[w * 16 + lq * 4 + r][col] = f2bf(silu_f(acc[r] + bb));
        __builtin_amdgcn_s_setprio(1);
    }
    __builtin_amdgcn_s_setprio(0);
    __syncthreads();    // all b_s reads done
    REGWRITE();         // W1 -> b_s
    __syncthreads();

    REGLOAD(Wt_lin);    // prefetch W_lin, hides under GEMM2
    bfrag a2[6];
    #pragma unroll
    for (int ks = 0; ks < 6; ++ks)
        a2[ks] = *(const bfrag*)&t_s[w * 16 + lr][ks * 32 + kq];

    // GEMM2: h1 = h + silu(t@W1+b1) -> t_s
    __builtin_amdgcn_s_setprio(1);
    #pragma unroll
    for (int t = 0; t < 12; ++t) {
        f32x4 acc = (f32x4){0.f, 0.f, 0.f, 0.f};
        #pragma unroll
        for (int ks = 0; ks < 6; ++ks) {
            bfrag b = *(const bfrag*)&b_s[t * 16 + lr][ks * 32 + kq];
            acc = MFMA16(a2[ks], b, acc);
        }
        __builtin_amdgcn_s_setprio(0);
        int col = t * 16 + lr;
        float bb = b1[col];
        #pragma unroll
        for (int r = 0; r < 4; ++r) {
            int rloc = w * 16 + lq * 4 + r;
            int grow = row0 + rloc;
            float h1 = 0.f;
            if (grow < E)
                h1 = bf2f(hB[(size_t)grow * HCH + col]) + silu_f(acc[r] + bb);
            t_s[rloc][col] = f2bf(h1);
        }
        __builtin_amdgcn_s_setprio(1);
    }
    __builtin_amdgcn_s_setprio(0);
    __syncthreads();
    REGWRITE();         // W_lin -> b_s
    __syncthreads();

    bfrag a3[6];
    #pragma unroll
    for (int ks = 0; ks < 6; ++ks)
        a3[ks] = *(const bfrag*)&t_s[w * 16 + lr][ks * 32 + kq];

    // GEMM3: hB = bf16( silu(h1@W_lin + b_lin) + x )
    __builtin_amdgcn_s_setprio(1);
    #pragma unroll
    for (int t = 0; t < 12; ++t) {
        f32x4 acc = (f32x4){0.f, 0.f, 0.f, 0.f};
        #pragma unroll
        for (int ks = 0; ks < 6; ++ks) {
            bfrag b = *(const bfrag*)&b_s[t * 16 + lr][ks * 32 + kq];
            acc = MFMA16(a3[ks], b, acc);
        }
        __builtin_amdgcn_s_setprio(0);
        int col = t * 16 + lr;
        float bb = b_lin[col];
        #pragma unroll
        for (int r = 0; r < 4; ++r) {
            int grow = row0 + w * 16 + lq * 4 + r;
            if (grow >= E) continue;
            size_t off = (size_t)grow * HCH + col;
            hB[off] = f2bf(silu_f(acc[r] + bb) + x[off]);
        }
        __builtin_amdgcn_s_setprio(1);
    }
    __builtin_amdgcn_s_setprio(0);
}

// ---------------- fused res_a0 + res_a1: prefetch + setprio, VGPR cap lifted ----------------
__global__ __launch_bounds__(512, 2) void resres_k(
    const unsigned short* __restrict__ hB, const unsigned short* __restrict__ Wt,
    const float* __restrict__ bias, float* __restrict__ out, int E)
{
    __shared__ unsigned short b_s[192][200];
    __shared__ unsigned short t_s[128][200];
    const int tid = threadIdx.x;
    const int lane = tid & 63, w = tid >> 6;
    const int row0 = blockIdx.x * 128;
    const int lr = lane & 15, lq = lane >> 4;
    const int kq = lq * 8;
    const int ra = row0 + w * 16 + lr;
    const bool rav = ra < E;

    uint4 wr[9];
    STAGE_B(Wt);                                     // W0
    bfrag a[6];
    #pragma unroll
    for (int ks = 0; ks < 6; ++ks)
        a[ks] = rav ? *(const bfrag*)(hB + (size_t)ra * HCH + ks * 32 + kq) : bzero();
    __syncthreads();

    REGLOAD(Wt + WSEG);   // prefetch W1

    // GEMM1: t1 = silu(h@W0+b0)
    __builtin_amdgcn_s_setprio(1);
    #pragma unroll
    for (int t = 0; t < 12; ++t) {
        f32x4 acc = (f32x4){0.f, 0.f, 0.f, 0.f};
        #pragma unroll
        for (int ks = 0; ks < 6; ++ks) {
            bfrag b = *(const bfrag*)&b_s[t * 16 + lr][ks * 32 + kq];
            acc = MFMA16(a[ks], b, acc);
        }
        __builtin_amdgcn_s_setprio(0);
        int col = t * 16 + lr;
        float bb = bias[col];
        #pragma unroll
        for (int r = 0; r < 4; ++r)
            t_s[w * 16 + lq * 4 + r][col] = f2bf(silu_f(acc[r] + bb));
        __builtin_amdgcn_s_setprio(1);
    }
    __builtin_amdgcn_s_setprio(0);
    __syncthreads();
    REGWRITE();          // W1
    __syncthreads();

    REGLOAD(Wt + 2 * WSEG);   // prefetch W2
    bfrag a2[6];
    #pragma unroll
    for (int ks = 0; ks < 6; ++ks)
        a2[ks] = *(const bfrag*)&t_s[w * 16 + lr][ks * 32 + kq];

    // GEMM2: h1 = h + silu(t1@W1+b1); fp32 in regs AND bf16 -> t_s
    float h1reg[12][4];
    __builtin_amdgcn_s_setprio(1);
    #pragma unroll
    for (int t = 0; t < 12; ++t) {
        f32x4 acc = (f32x4){0.f, 0.f, 0.f, 0.f};
        #pragma unroll
        for (int ks = 0; ks < 6; ++ks) {
            bfrag b = *(const bfrag*)&b_s[t * 16 + lr][ks * 32 + kq];
            acc = MFMA16(a2[ks], b, acc);
        }
        __builtin_amdgcn_s_setprio(0);
        int col = t * 16 + lr;
        float bb = bias[HCH + col];
        #pragma unroll
        for (int r = 0; r < 4; ++r) {
            int rloc = w * 16 + lq * 4 + r;
            int grow = row0 + rloc;
            float h1 = 0.f;
            if (grow < E)
                h1 = bf2f(hB[(size_t)grow * HCH + col]) + silu_f(acc[r] + bb);
            h1reg[t][r] = h1;
            t_s[rloc][col] = f2bf(h1);
        }
        __builtin_amdgcn_s_setprio(1);
    }
    __builtin_amdgcn_s_setprio(0);
    __syncthreads();
    REGWRITE();          // W2
    __syncthreads();

    REGLOAD(Wt + 3 * WSEG);   // prefetch W3
    bfrag a3[6];
    #pragma unroll
    for (int ks = 0; ks < 6; ++ks)
        a3[ks] = *(const bfrag*)&t_s[w * 16 + lr][ks * 32 + kq];

    // GEMM3: t2 = silu(h1@W2+b2) -> t_s
    __builtin_amdgcn_s_setprio(1);
    #pragma unroll
    for (int t = 0; t < 12; ++t) {
        f32x4 acc = (f32x4){0.f, 0.f, 0.f, 0.f};
        #pragma unroll
        for (int ks = 0; ks < 6; ++ks) {
            bfrag b = *(const bfrag*)&b_s[t * 16 + lr][ks * 32 + kq];
            acc = MFMA16(a3[ks], b, acc);
        }
        __builtin_amdgcn_s_setprio(0);
        int col = t * 16 + lr;
        float bb = bias[2 * HCH + col];
        #pragma unroll
        for (int r = 0; r < 4; ++r)
            t_s[w * 16 + lq * 4 + r][col] = f2bf(silu_f(acc[r] + bb));
        __builtin_amdgcn_s_setprio(1);
    }
    __builtin_amdgcn_s_setprio(0);
    __syncthreads();
    REGWRITE();          // W3
    __syncthreads();

    bfrag a4[6];
    #pragma unroll
    for (int ks = 0; ks < 6; ++ks)
        a4[ks] = *(const bfrag*)&t_s[w * 16 + lr][ks * 32 + kq];

    // GEMM4: out = h1 + silu(t2@W3+b3)   (fp32 out, fp32 h1 from regs)
    __builtin_amdgcn_s_setprio(1);
    #pragma unroll
    for (int t = 0; t < 12; ++t) {
        f32x4 acc = (f32x4){0.f, 0.f, 0.f, 0.f};
        #pragma unroll
        for (int ks = 0; ks < 6; ++ks) {
            bfrag b = *(const bfrag*)&b_s[t * 16 + lr][ks * 32 + kq];
            acc = MFMA16(a4[ks], b, acc);
        }
        __builtin_amdgcn_s_setprio(0);
        int col = t * 16 + lr;
        float bb = bias[3 * HCH + col];
        #pragma unroll
        for (int r = 0; r < 4; ++r) {
            int grow = row0 + w * 16 + lq * 4 + r;
            if (grow >= E) continue;
            out[(size_t)grow * HCH + col] = h1reg[t][r] + silu_f(acc[r] + bb);
        }
        __builtin_amdgcn_s_setprio(1);
    }
    __builtin_amdgcn_s_setprio(0);
}

// ---------------- CSR scatter->gather pipeline (round-13, proven) ----------------
__global__ __launch_bounds__(256) void pcount_k(
    const float* __restrict__ sbf, const int* __restrict__ idx_ji,
    const float* __restrict__ w1, unsigned short* __restrict__ pB,
    int* __restrict__ counts, int T)
{
    int t = blockIdx.x * 256 + threadIdx.x;
    if (t >= T) return;
    const float* sp = sbf + (size_t)t * SBFD;
    float acc[8];
    #pragma unroll
    for (int b = 0; b < 8; ++b) acc[b] = 0.f;
    #pragma unroll
    for (int r = 0; r < 40; r += 4) {
        float4 v = *(const float4*)(sp + r);
        #pragma unroll
        for (int b = 0; b < 8; ++b)
            acc[b] += v.x * w1[r * 8 + b] + v.y * w1[(r + 1) * 8 + b]
                    + v.z * w1[(r + 2) * 8 + b] + v.w * w1[(r + 3) * 8 + b];
    }
    {
        float2 v = *(const float2*)(sp + 40);
        #pragma unroll
        for (int b = 0; b < 8; ++b)
            acc[b] += v.x * w1[40 * 8 + b] + v.y * w1[41 * 8 + b];
    }
    uint4 pk;
    pk.x = f2bf2(acc[0], acc[1]);
    pk.y = f2bf2(acc[2], acc[3]);
    pk.z = f2bf2(acc[4], acc[5]);
    pk.w = f2bf2(acc[6], acc[7]);
    *(uint4*)(pB + (size_t)t * 8) = pk;
    atomicAdd(&counts[idx_ji[t]], 1);
}

__global__ __launch_bounds__(256) void psum1_k(const int* __restrict__ counts,
                                               int* __restrict__ bsum, int E) {
    __shared__ int s[256];
    int base = blockIdx.x * 1024;
    int tid = threadIdx.x;
    int sum = 0;
    #pragma unroll
    for (int j = 0; j < 4; ++j) { int i = base + j * 256 + tid; if (i < E) sum += counts[i]; }
    s[tid] = sum; __syncthreads();
    for (int off = 128; off > 0; off >>= 1) {
        if (tid < off) s[tid] += s[tid + off];
        __syncthreads();
    }
    if (tid == 0) bsum[blockIdx.x] = s[0];
}

__global__ __launch_bounds__(512) void psum2_k(int* bsum, int G) {
    __shared__ int s[512];
    int tid = threadIdx.x;
    s[tid] = (tid < G) ? bsum[tid] : 0;
    for (int off = 1; off < 512; off <<= 1) {
        __syncthreads();
        int v = (tid >= off) ? s[tid - off] : 0;
        __syncthreads();
        s[tid] += v;
    }
    __syncthreads();
    if (tid < G) bsum[tid] = (tid == 0) ? 0 : s[tid - 1];
}

__global__ __launch_bounds__(256) void psum3_k(const int* __restrict__ counts,
                                               const int* __restrict__ bsum,
                                               int* __restrict__ start, int E) {
    __shared__ int s[256];
    int tid = threadIdx.x;
    int base = blockIdx.x * 1024 + tid * 4;
    int v[4]; int loc = 0;
    #pragma unroll
    for (int j = 0; j < 4; ++j) { v[j] = (base + j < E) ? counts[base + j] : 0; loc += v[j]; }
    s[tid] = loc;
    for (int off = 1; off < 256; off <<= 1) {
        __syncthreads();
        int t2 = (tid >= off) ? s[tid - off] : 0;
        __syncthreads();
        s[tid] += t2;
    }
    __syncthreads();
    int run = bsum[blockIdx.x] + s[tid] - loc;
    #pragma unroll
    for (int j = 0; j < 4; ++j) { if (base + j < E) start[base + j] = run; run += v[j]; }
}

// fill: materialize kj and p streams in bucket order
__global__ __launch_bounds__(256) void fill_k(
    const int* __restrict__ idx_ji, const int* __restrict__ idx_kj,
    const unsigned short* __restrict__ pB, int* __restrict__ start,
    int* __restrict__ kjs, unsigned short* __restrict__ pSort, int T)
{
    int t = blockIdx.x * 256 + threadIdx.x;
    if (t >= T) return;
    int pos = atomicAdd(&start[idx_ji[t]], 1);
    kjs[pos] = idx_kj[t];
    *(uint4*)(pSort + (size_t)pos * 8) = *(const uint4*)(pB + (size_t)t * 8);
}

// gather: sequential kjs/pSort streams; only x64b row-gather is random (L3-hot)
__global__ __launch_bounds__(256) void gather_k(
    const int* __restrict__ kjs, const unsigned short* __restrict__ pSort,
    const unsigned short* __restrict__ x64b, const int* __restrict__ start,
    const int* __restrict__ counts, const float* __restrict__ w2,
    unsigned short* __restrict__ aggB, int E)
{
    int tid = threadIdx.x;
    int wave = (blockIdx.x * 256 + tid) >> 6;
    int lane = tid & 63;
    if (wave >= E) return;

    float wcol[8];
    #pragma unroll
    for (int b = 0; b < 8; ++b) wcol[b] = w2[b * 64 + lane];

    int n = counts[wave];
    int end = start[wave];
    int i = end - n;

    float acc = 0.f;
    for (; i + 4 <= end; i += 4) {
        int k0 = kjs[i], k1 = kjs[i + 1], k2 = kjs[i + 2], k3 = kjs[i + 3];
        uint4 q0 = *(const uint4*)(pSort + (size_t)i * 8);
        uint4 q1 = *(const uint4*)(pSort + (size_t)(i + 1) * 8);
        uint4 q2 = *(const uint4*)(pSort + (size_t)(i + 2) * 8);
        uint4 q3 = *(const uint4*)(pSort + (size_t)(i + 3) * 8);
        float x0 = bf2f(x64b[(size_t)k0 * ICH + lane]);
        float x1 = bf2f(x64b[(size_t)k1 * ICH + lane]);
        float x2 = bf2f(x64b[(size_t)k2 * ICH + lane]);
        float x3 = bf2f(x64b[(size_t)k3 * ICH + lane]);
        float s0 = lo16(q0.x)*wcol[0] + hi16(q0.x)*wcol[1] + lo16(q0.y)*wcol[2] + hi16(q0.y)*wcol[3]
                 + lo16(q0.z)*wcol[4] + hi16(q0.z)*wcol[5] + lo16(q0.w)*wcol[6] + hi16(q0.w)*wcol[7];
        float s1 = lo16(q1.x)*wcol[0] + hi16(q1.x)*wcol[1] + lo16(q1.y)*wcol[2] + hi16(q1.y)*wcol[3]
                 + lo16(q1.z)*wcol[4] + hi16(q1.z)*wcol[5] + lo16(q1.w)*wcol[6] + hi16(q1.w)*wcol[7];
        float s2 = lo16(q2.x)*wcol[0] + hi16(q2.x)*wcol[1] + lo16(q2.y)*wcol[2] + hi16(q2.y)*wcol[3]
                 + lo16(q2.z)*wcol[4] + hi16(q2.z)*wcol[5] + lo16(q2.w)*wcol[6] + hi16(q2.w)*wcol[7];
        float s3 = lo16(q3.x)*wcol[0] + hi16(q3.x)*wcol[1] + lo16(q3.y)*wcol[2] + hi16(q3.y)*wcol[3]
                 + lo16(q3.z)*wcol[4] + hi16(q3.z)*wcol[5] + lo16(q3.w)*wcol[6] + hi16(q3.w)*wcol[7];
        acc += s0 * x0 + s1 * x1 + s2 * x2 + s3 * x3;
    }
    for (; i < end; ++i) {
        int kj = kjs[i];
        uint4 q = *(const uint4*)(pSort + (size_t)i * 8);
        float xv = bf2f(x64b[(size_t)kj * ICH + lane]);
        float sc = lo16(q.x)*wcol[0] + hi16(q.x)*wcol[1] + lo16(q.y)*wcol[2] + hi16(q.y)*wcol[3]
                 + lo16(q.z)*wcol[4] + hi16(q.z)*wcol[5] + lo16(q.w)*wcol[6] + hi16(q.w)*wcol[7];
        acc += sc * xv;
    }
    aggB[(size_t)wave * ICH + lane] = f2bf(acc);
}

extern "C" void kernel_launch(void* const* d_in, const int* in_sizes, int n_in,
                              void* d_out, int out_size, void* d_ws, size_t ws_size,
                              hipStream_t stream) {
    const float* x      = (const float*)d_in[0];
    const float* rbf    = (const float*)d_in[1];
    const float* sbf    = (const float*)d_in[2];
    const int*   idx_kj = (const int*)d_in[3];
    const int*   idx_ji = (const int*)d_in[4];
    const float* W_rbf1 = (const float*)d_in[5];
    const float* W_rbf2 = (const float*)d_in[6];
    const float* W_sbf1 = (const float*)d_in[7];
    const float* W_sbf2 = (const float*)d_in[8];
    const float* W_kj   = (const float*)d_in[9];
    const float* b_kj   = (const float*)d_in[10];
    const float* W_ji   = (const float*)d_in[11];
    const float* b_ji   = (const float*)d_in[12];
    const float* W_down = (const float*)d_in[13];
    const float* W_up   = (const float*)d_in[14];
    const float* resbW  = (const float*)d_in[15];
    const float* resbB  = (const float*)d_in[16];
    const float* W_lin  = (const float*)d_in[17];
    const float* b_lin  = (const float*)d_in[18];
    const float* resaW  = (const float*)d_in[19];
    const float* resaB  = (const float*)d_in[20];

    const int E = in_sizes[0] / HCH;
    const int T = in_sizes[3];
    float* out = (float*)d_out;

    // ws: wc_rbf f32[1152] | counts[E] | start[E] | bsum[512] | kjs[T] |
    //     pB u16[T*8] | pSort u16[T*8] | x64b u16[E*64] | aggB u16[E*64] |
    //     hB u16[E*192] | Wt u16[WT_TOTAL]
    float* wc_rbf = (float*)d_ws;
    int*   counts = (int*)(wc_rbf + NRAD * HCH);
    int*   start  = counts + E;
    int*   bsum   = start + E;
    int*   kjs    = bsum + 512;
    unsigned short* pB    = (unsigned short*)(kjs + T);
    unsigned short* pSort = pB + (size_t)T * 8;
    unsigned short* x64b  = pSort + (size_t)T * 8;
    unsigned short* aggB  = x64b + (size_t)E * ICH;
    unsigned short* hB    = aggB + (size_t)E * ICH;
    unsigned short* Wt    = hB + (size_t)E * HCH;

    const unsigned short* Wt_kj   = Wt;
    const unsigned short* Wt_ji   = Wt + 1 * WSEG;
    const unsigned short* Wt_lin  = Wt + 2 * WSEG;
    const unsigned short* Wt_rb0  = Wt + 3 * WSEG;   // W0, W1 at +WSEG
    const unsigned short* Wt_ra   = Wt + 5 * WSEG;   // ra0_0, ra0_1, ra1_0, ra1_1
    const unsigned short* Wt_down = Wt + WT_DOWN;
    const unsigned short* Wt_up   = Wt + WT_UP;

    const int gb128 = (E + 127) / 128;
    const int gt = (T + 255) / 256;
    const int gscan = (E + 1023) / 1024;

    wc_k<<<(NRAD * HCH + NT - 1) / NT, NT, 0, stream>>>(W_rbf1, W_rbf2, wc_rbf);
    prep_k<<<(WT_TOTAL + NT - 1) / NT, NT, 0, stream>>>(W_kj, W_ji, W_lin, resbW, resaW,
                                                        W_down, W_up, Wt);

    // CSR build + stream materialization
    hipMemsetAsync(counts, 0, (size_t)E * sizeof(int), stream);
    pcount_k<<<gt, 256, 0, stream>>>(sbf, idx_ji, W_sbf1, pB, counts, T);
    psum1_k<<<gscan, 256, 0, stream>>>(counts, bsum, E);
    psum2_k<<<1, 512, 0, stream>>>(bsum, gscan);
    psum3_k<<<gscan, 256, 0, stream>>>(counts, bsum, start, E);
    fill_k<<<gt, 256, 0, stream>>>(idx_ji, idx_kj, pB, start, kjs, pSort, T);

    // x -> x64b (bf16), B via LDS + prefetch
    fused12_k<<<gb128, 512, 0, stream>>>(x, Wt_kj, b_kj, rbf, wc_rbf, Wt_down, x64b, E);
    // aggB = segment_sum(x64b[kjs] * (pSort@W_sbf2))
    gather_k<<<(E + 3) / 4, 256, 0, stream>>>(kjs, pSort, x64b, start, counts, W_sbf2, aggB, E);
    // hB = silu(x@W_ji+b) + silu(agg@W_up), B via LDS
    combine_k<<<gb128, 512, 0, stream>>>(x, Wt_ji, b_ji, aggB, Wt_up, hB, E);
    // res_before + lin fused (prefetch + setprio, spill-free)
    reslin_k<<<gb128, 512, 0, stream>>>(hB, Wt_rb0, Wt_rb0 + WSEG, Wt_lin,
                                        resbB, resbB + HCH, b_lin, x, E);
    // res_after x2 fused (prefetch + setprio, spill-free), fp32 out
    resres_k<<<gb128, 512, 0, stream>>>(hB, Wt_ra, resaB, out, E);
}

// Round 17
// 2019.372 us; speedup vs baseline: 1.2848x; 1.2821x over previous
//
#include <hip/hip_runtime.h>
#include <cstdint>
#include <cstddef>

#define HCH 192
#define ICH 64
#define NRAD 6
#define SBFD 42

constexpr int NT = 256;

using bfrag = __attribute__((ext_vector_type(8))) short;  // 8 bf16 (4 VGPRs)
using f32x4 = __attribute__((ext_vector_type(4))) float;

#define MFMA16(a, b, c) __builtin_amdgcn_mfma_f32_16x16x32_bf16(a, b, c, 0, 0, 0)

__device__ __forceinline__ float silu_f(float v) {
    return v / (1.0f + __expf(-v));
}

__device__ __forceinline__ unsigned short f2bf(float x) {
    union { float f; unsigned u; } v; v.f = x;
    return (unsigned short)((v.u + 0x7FFFu + ((v.u >> 16) & 1u)) >> 16);
}

__device__ __forceinline__ unsigned f2bf2(float a, float b) {
    return (unsigned)f2bf(a) | ((unsigned)f2bf(b) << 16);
}

__device__ __forceinline__ float bf2f(unsigned short u) {
    union { unsigned u; float f; } v; v.u = ((unsigned)u) << 16;
    return v.f;
}

__device__ __forceinline__ float lo16(unsigned u) {
    union { unsigned x; float f; } v; v.x = u << 16; return v.f;
}
__device__ __forceinline__ float hi16(unsigned u) {
    union { unsigned x; float f; } v; v.x = u & 0xffff0000u; return v.f;
}

__device__ __forceinline__ bfrag pack8(float4 a, float4 b) {
    bfrag r;
    r[0] = (short)f2bf(a.x); r[1] = (short)f2bf(a.y);
    r[2] = (short)f2bf(a.z); r[3] = (short)f2bf(a.w);
    r[4] = (short)f2bf(b.x); r[5] = (short)f2bf(b.y);
    r[6] = (short)f2bf(b.z); r[7] = (short)f2bf(b.w);
    return r;
}

__device__ __forceinline__ bfrag bzero() {
    bfrag r;
    #pragma unroll
    for (int i = 0; i < 8; ++i) r[i] = 0;
    return r;
}

// stage a [192][192] bf16 panel into b_s[192][200] with 512 threads (9 uint4/thread)
#define STAGE_B(SRC)                                                             \
    {                                                                            \
        _Pragma("unroll")                                                        \
        for (int it = 0; it < 9; ++it) {                                         \
            int idx = it * 512 + tid;                                            \
            int r = idx / 24, c8 = idx % 24;                                     \
            *(uint4*)&b_s[r][c8 * 8] = *(const uint4*)((SRC) + (size_t)r * HCH + c8 * 8); \
        }                                                                        \
    }

// ---------------- weight prep: fp32 [K][N] -> bf16 transposed [N][K] ----------------
#define WSEG 36864
#define WT_DOWN (9 * WSEG)
#define WT_UP   (9 * WSEG + 12288)
#define WT_TOTAL (9 * WSEG + 2 * 12288)

__global__ __launch_bounds__(NT) void prep_k(
    const float* __restrict__ W_kj, const float* __restrict__ W_ji,
    const float* __restrict__ W_lin, const float* __restrict__ resbW,
    const float* __restrict__ resaW, const float* __restrict__ W_down,
    const float* __restrict__ W_up, unsigned short* __restrict__ Wt)
{
    int i = blockIdx.x * NT + threadIdx.x;
    if (i < 9 * WSEG) {
        int seg = i / WSEG, r = i % WSEG;
        int k = r / HCH, n = r % HCH;
        const float* src =
            seg == 0 ? W_kj : seg == 1 ? W_ji : seg == 2 ? W_lin :
            seg <= 4 ? resbW + (seg - 3) * WSEG : resaW + (seg - 5) * WSEG;
        Wt[seg * WSEG + n * HCH + k] = f2bf(src[r]);
    } else if (i < WT_DOWN + 12288) {
        int r = i - WT_DOWN;
        int k = r / ICH, n = r % ICH;           // W_down [192][64]
        Wt[WT_DOWN + n * HCH + k] = f2bf(W_down[r]);
    } else if (i < WT_TOTAL) {
        int r = i - WT_UP;
        int k = r / HCH, n = r % HCH;           // W_up [64][192]
        Wt[WT_UP + n * ICH + k] = f2bf(W_up[r]);
    }
}

// wc_rbf[6,192] = W_rbf1[6,8] @ W_rbf2[8,192]  (kept fp32)
__global__ void wc_k(const float* __restrict__ W_rbf1, const float* __restrict__ W_rbf2,
                     float* __restrict__ wc)
{
    int tid = blockIdx.x * blockDim.x + threadIdx.x;
    if (tid < NRAD * HCH) {
        int r = tid / HCH, c = tid % HCH;
        float a = 0.f;
        #pragma unroll
        for (int b = 0; b < 8; ++b) a += W_rbf1[r * 8 + b] * W_rbf2[b * HCH + c];
        wc[tid] = a;
    }
}

// ---------------- head: x -> x64b (bf16), B staged in LDS (round-13, proven) ----------------
__global__ __launch_bounds__(512) void fused12_k(
    const float* __restrict__ x, const unsigned short* __restrict__ Wt_kj,
    const float* __restrict__ b_kj, const float* __restrict__ rbf,
    const float* __restrict__ wc, const unsigned short* __restrict__ Wt_down,
    unsigned short* __restrict__ x64b, int E)
{
    __shared__ unsigned short b_s[192][200];
    __shared__ unsigned short u_s[128][200];
    __shared__ float wc_s[NRAD * HCH];
    const int tid = threadIdx.x;
    const int lane = tid & 63, w = tid >> 6;
    const int row0 = blockIdx.x * 128;
    const int lr = lane & 15, lq = lane >> 4;
    const int kq = lq * 8;
    const int ra = row0 + w * 16 + lr;
    const bool rav = ra < E;

    STAGE_B(Wt_kj);
    for (int i = tid; i < NRAD * HCH; i += 512) wc_s[i] = wc[i];

    bfrag a[6];
    #pragma unroll
    for (int ks = 0; ks < 6; ++ks) {
        float4 a0 = make_float4(0,0,0,0), a1 = make_float4(0,0,0,0);
        if (rav) {
            a0 = *(const float4*)(x + (size_t)ra * HCH + ks * 32 + kq);
            a1 = *(const float4*)(x + (size_t)ra * HCH + ks * 32 + kq + 4);
        }
        a[ks] = pack8(a0, a1);
    }
    float rb[4][NRAD];
    #pragma unroll
    for (int r = 0; r < 4; ++r) {
        int grow = row0 + w * 16 + lq * 4 + r;
        #pragma unroll
        for (int q = 0; q < NRAD; ++q)
            rb[r][q] = (grow < E) ? rbf[(size_t)grow * NRAD + q] : 0.f;
    }
    __syncthreads();

    #pragma unroll
    for (int t = 0; t < 12; ++t) {
        f32x4 acc = (f32x4){0.f, 0.f, 0.f, 0.f};
        #pragma unroll
        for (int ks = 0; ks < 6; ++ks) {
            bfrag b = *(const bfrag*)&b_s[t * 16 + lr][ks * 32 + kq];
            acc = MFMA16(a[ks], b, acc);
        }
        int col = t * 16 + lr;
        float bb = b_kj[col];
        #pragma unroll
        for (int r = 0; r < 4; ++r) {
            float sv = silu_f(acc[r] + bb);
            float rh = 0.f;
            #pragma unroll
            for (int q = 0; q < NRAD; ++q) rh += rb[r][q] * wc_s[q * HCH + col];
            u_s[w * 16 + lq * 4 + r][col] = f2bf(sv * rh);
        }
    }
    __syncthreads();

    #pragma unroll
    for (int it = 0; it < 3; ++it) {
        int idx = it * 512 + tid;
        int r = idx / 24, c8 = idx % 24;
        *(uint4*)&b_s[r][c8 * 8] = *(const uint4*)(Wt_down + (size_t)r * HCH + c8 * 8);
    }
    bfrag a2[6];
    #pragma unroll
    for (int ks = 0; ks < 6; ++ks)
        a2[ks] = *(const bfrag*)&u_s[w * 16 + lr][ks * 32 + kq];
    __syncthreads();

    float o[4][4];
    #pragma unroll
    for (int t = 0; t < 4; ++t) {
        f32x4 acc = (f32x4){0.f, 0.f, 0.f, 0.f};
        #pragma unroll
        for (int ks = 0; ks < 6; ++ks) {
            bfrag b = *(const bfrag*)&b_s[t * 16 + lr][ks * 32 + kq];
            acc = MFMA16(a2[ks], b, acc);
        }
        #pragma unroll
        for (int r = 0; r < 4; ++r) o[t][r] = silu_f(acc[r]);
    }
    __syncthreads();
    #pragma unroll
    for (int t = 0; t < 4; ++t)
        #pragma unroll
        for (int r = 0; r < 4; ++r)
            u_s[w * 16 + lq * 4 + r][t * 16 + lr] = f2bf(o[t][r]);
    __syncthreads();

    #pragma unroll
    for (int it = 0; it < 2; ++it) {
        int idx = it * 512 + tid;
        int r = idx >> 3, c8 = (idx & 7) * 8;
        int grow = row0 + r;
        if (grow < E)
            *(uint4*)(x64b + (size_t)grow * ICH + c8) = *(const uint4*)&u_s[r][c8];
    }
}

// ---------------- fused combine + res_b0 + lin (4 phases; h carried fp32 in regs) ----------------
// P0: h = silu(x@W_ji+b_ji) + silu(agg@W_up)     (hreg + t_s)
// P1: t = silu(h@W0+b0)                          (t_s)
// P2: h1 = hreg + silu(t@W1+b1)                  (t_s)
// P3: hB = bf16( silu(h1@W_lin+b_lin) + x )      (global)
__global__ __launch_bounds__(512) void creslin_k(
    const float* __restrict__ x, const unsigned short* __restrict__ Wt_ji,
    const float* __restrict__ b_ji, const unsigned short* __restrict__ aggB,
    const unsigned short* __restrict__ Wt_up,
    const unsigned short* __restrict__ Wt0, const unsigned short* __restrict__ Wt1,
    const unsigned short* __restrict__ Wt_lin,
    const float* __restrict__ b0, const float* __restrict__ b1,
    const float* __restrict__ b_lin, unsigned short* __restrict__ hB, int E)
{
    __shared__ unsigned short b_s[192][200];   // 76.8 KB
    __shared__ unsigned short t_s[128][200];   // 51.2 KB (wave-private rows)
    __shared__ unsigned short bu_s[192][72];   // 27.6 KB (W_up, read only in P0)
    const int tid = threadIdx.x;
    const int lane = tid & 63, w = tid >> 6;
    const int row0 = blockIdx.x * 128;
    const int lr = lane & 15, lq = lane >> 4;
    const int kq = lq * 8;
    const int ra = row0 + w * 16 + lr;
    const bool rav = ra < E;

    STAGE_B(Wt_ji);
    #pragma unroll
    for (int it = 0; it < 3; ++it) {
        int idx = it * 512 + tid;
        int r = idx / 8, c8 = idx % 8;
        *(uint4*)&bu_s[r][c8 * 8] = *(const uint4*)(Wt_up + (size_t)r * ICH + c8 * 8);
    }

    bfrag aag[2], ax[6];
    #pragma unroll
    for (int ks = 0; ks < 2; ++ks)
        aag[ks] = rav ? *(const bfrag*)(aggB + (size_t)ra * ICH + ks * 32 + kq) : bzero();
    #pragma unroll
    for (int ks = 0; ks < 6; ++ks) {
        float4 a0 = make_float4(0,0,0,0), a1 = make_float4(0,0,0,0);
        if (rav) {
            a0 = *(const float4*)(x + (size_t)ra * HCH + ks * 32 + kq);
            a1 = *(const float4*)(x + (size_t)ra * HCH + ks * 32 + kq + 4);
        }
        ax[ks] = pack8(a0, a1);
    }
    __syncthreads();

    // P0: h = silu(x@W_ji + b_ji) + silu(agg@W_up); keep fp32 in hreg, bf16 -> t_s
    float hreg[12][4];
    #pragma unroll
    for (int t = 0; t < 12; ++t) {
        f32x4 au = (f32x4){0.f, 0.f, 0.f, 0.f};
        #pragma unroll
        for (int ks = 0; ks < 2; ++ks) {
            bfrag bu = *(const bfrag*)&bu_s[t * 16 + lr][ks * 32 + kq];
            au = MFMA16(aag[ks], bu, au);
        }
        f32x4 aj = (f32x4){0.f, 0.f, 0.f, 0.f};
        #pragma unroll
        for (int ks = 0; ks < 6; ++ks) {
            bfrag b = *(const bfrag*)&b_s[t * 16 + lr][ks * 32 + kq];
            aj = MFMA16(ax[ks], b, aj);
        }
        int col = t * 16 + lr;
        float bb = b_ji[col];
        #pragma unroll
        for (int r = 0; r < 4; ++r) {
            float h = silu_f(aj[r] + bb) + silu_f(au[r]);
            hreg[t][r] = h;
            t_s[w * 16 + lq * 4 + r][col] = f2bf(h);
        }
    }
    __syncthreads();      // b_s reads done; t_s(h) visible

    STAGE_B(Wt0);
    bfrag a1[6];
    #pragma unroll
    for (int ks = 0; ks < 6; ++ks)
        a1[ks] = *(const bfrag*)&t_s[w * 16 + lr][ks * 32 + kq];
    __syncthreads();

    // P1: t = silu(h@W0+b0) -> t_s
    #pragma unroll
    for (int t = 0; t < 12; ++t) {
        f32x4 acc = (f32x4){0.f, 0.f, 0.f, 0.f};
        #pragma unroll
        for (int ks = 0; ks < 6; ++ks) {
            bfrag b = *(const bfrag*)&b_s[t * 16 + lr][ks * 32 + kq];
            acc = MFMA16(a1[ks], b, acc);
        }
        int col = t * 16 + lr;
        float bb = b0[col];
        #pragma unroll
        for (int r = 0; r < 4; ++r)
            t_s[w * 16 + lq * 4 + r][col] = f2bf(silu_f(acc[r] + bb));
    }
    __syncthreads();

    STAGE_B(Wt1);
    bfrag a2[6];
    #pragma unroll
    for (int ks = 0; ks < 6; ++ks)
        a2[ks] = *(const bfrag*)&t_s[w * 16 + lr][ks * 32 + kq];
    __syncthreads();

    // P2: h1 = hreg + silu(t@W1+b1) -> t_s
    #pragma unroll
    for (int t = 0; t < 12; ++t) {
        f32x4 acc = (f32x4){0.f, 0.f, 0.f, 0.f};
        #pragma unroll
        for (int ks = 0; ks < 6; ++ks) {
            bfrag b = *(const bfrag*)&b_s[t * 16 + lr][ks * 32 + kq];
            acc = MFMA16(a2[ks], b, acc);
        }
        int col = t * 16 + lr;
        float bb = b1[col];
        #pragma unroll
        for (int r = 0; r < 4; ++r) {
            float h1 = hreg[t][r] + silu_f(acc[r] + bb);
            t_s[w * 16 + lq * 4 + r][col] = f2bf(h1);
        }
    }
    __syncthreads();

    STAGE_B(Wt_lin);
    bfrag a3[6];
    #pragma unroll
    for (int ks = 0; ks < 6; ++ks)
        a3[ks] = *(const bfrag*)&t_s[w * 16 + lr][ks * 32 + kq];
    __syncthreads();

    // P3: hB = bf16( silu(h1@W_lin + b_lin) + x )
    #pragma unroll
    for (int t = 0; t < 12; ++t) {
        f32x4 acc = (f32x4){0.f, 0.f, 0.f, 0.f};
        #pragma unroll
        for (int ks = 0; ks < 6; ++ks) {
            bfrag b = *(const bfrag*)&b_s[t * 16 + lr][ks * 32 + kq];
            acc = MFMA16(a3[ks], b, acc);
        }
        int col = t * 16 + lr;
        float bb = b_lin[col];
        #pragma unroll
        for (int r = 0; r < 4; ++r) {
            int grow = row0 + w * 16 + lq * 4 + r;
            if (grow >= E) continue;
            size_t off = (size_t)grow * HCH + col;
            hB[off] = f2bf(silu_f(acc[r] + bb) + x[off]);
        }
    }
}

// ---------------- fused res_a0 + res_a1 (round-13, proven) ----------------
__global__ __launch_bounds__(512) void resres_k(
    const unsigned short* __restrict__ hB, const unsigned short* __restrict__ Wt,
    const float* __restrict__ bias, float* __restrict__ out, int E)
{
    __shared__ unsigned short b_s[192][200];
    __shared__ unsigned short t_s[128][200];
    const int tid = threadIdx.x;
    const int lane = tid & 63, w = tid >> 6;
    const int row0 = blockIdx.x * 128;
    const int lr = lane & 15, lq = lane >> 4;
    const int kq = lq * 8;
    const int ra = row0 + w * 16 + lr;
    const bool rav = ra < E;

    STAGE_B(Wt);                                     // W0
    bfrag a[6];
    #pragma unroll
    for (int ks = 0; ks < 6; ++ks)
        a[ks] = rav ? *(const bfrag*)(hB + (size_t)ra * HCH + ks * 32 + kq) : bzero();
    __syncthreads();

    // GEMM1: t1 = silu(h@W0+b0)
    #pragma unroll
    for (int t = 0; t < 12; ++t) {
        f32x4 acc = (f32x4){0.f, 0.f, 0.f, 0.f};
        #pragma unroll
        for (int ks = 0; ks < 6; ++ks) {
            bfrag b = *(const bfrag*)&b_s[t * 16 + lr][ks * 32 + kq];
            acc = MFMA16(a[ks], b, acc);
        }
        int col = t * 16 + lr;
        float bb = bias[col];
        #pragma unroll
        for (int r = 0; r < 4; ++r)
            t_s[w * 16 + lq * 4 + r][col] = f2bf(silu_f(acc[r] + bb));
    }
    __syncthreads();

    STAGE_B(Wt + WSEG);                              // W1
    bfrag a2[6];
    #pragma unroll
    for (int ks = 0; ks < 6; ++ks)
        a2[ks] = *(const bfrag*)&t_s[w * 16 + lr][ks * 32 + kq];
    __syncthreads();

    // GEMM2: h1 = h + silu(t1@W1+b1); kept fp32 in regs AND bf16 in t_s
    float h1reg[12][4];
    #pragma unroll
    for (int t = 0; t < 12; ++t) {
        f32x4 acc = (f32x4){0.f, 0.f, 0.f, 0.f};
        #pragma unroll
        for (int ks = 0; ks < 6; ++ks) {
            bfrag b = *(const bfrag*)&b_s[t * 16 + lr][ks * 32 + kq];
            acc = MFMA16(a2[ks], b, acc);
        }
        int col = t * 16 + lr;
        float bb = bias[HCH + col];
        #pragma unroll
        for (int r = 0; r < 4; ++r) {
            int rloc = w * 16 + lq * 4 + r;
            int grow = row0 + rloc;
            float h1 = 0.f;
            if (grow < E)
                h1 = bf2f(hB[(size_t)grow * HCH + col]) + silu_f(acc[r] + bb);
            h1reg[t][r] = h1;
            t_s[rloc][col] = f2bf(h1);
        }
    }
    __syncthreads();

    STAGE_B(Wt + 2 * WSEG);                          // W2
    bfrag a3[6];
    #pragma unroll
    for (int ks = 0; ks < 6; ++ks)
        a3[ks] = *(const bfrag*)&t_s[w * 16 + lr][ks * 32 + kq];
    __syncthreads();

    // GEMM3: t2 = silu(h1@W2+b2) -> t_s
    #pragma unroll
    for (int t = 0; t < 12; ++t) {
        f32x4 acc = (f32x4){0.f, 0.f, 0.f, 0.f};
        #pragma unroll
        for (int ks = 0; ks < 6; ++ks) {
            bfrag b = *(const bfrag*)&b_s[t * 16 + lr][ks * 32 + kq];
            acc = MFMA16(a3[ks], b, acc);
        }
        int col = t * 16 + lr;
        float bb = bias[2 * HCH + col];
        #pragma unroll
        for (int r = 0; r < 4; ++r)
            t_s[w * 16 + lq * 4 + r][col] = f2bf(silu_f(acc[r] + bb));
    }
    __syncthreads();

    STAGE_B(Wt + 3 * WSEG);                          // W3
    bfrag a4[6];
    #pragma unroll
    for (int ks = 0; ks < 6; ++ks)
        a4[ks] = *(const bfrag*)&t_s[w * 16 + lr][ks * 32 + kq];
    __syncthreads();

    // GEMM4: out = h1 + silu(t2@W3+b3)   (fp32 out, fp32 h1 from regs)
    #pragma unroll
    for (int t = 0; t < 12; ++t) {
        f32x4 acc = (f32x4){0.f, 0.f, 0.f, 0.f};
        #pragma unroll
        for (int ks = 0; ks < 6; ++ks) {
            bfrag b = *(const bfrag*)&b_s[t * 16 + lr][ks * 32 + kq];
            acc = MFMA16(a4[ks], b, acc);
        }
        int col = t * 16 + lr;
        float bb = bias[3 * HCH + col];
        #pragma unroll
        for (int r = 0; r < 4; ++r) {
            int grow = row0 + w * 16 + lq * 4 + r;
            if (grow >= E) continue;
            out[(size_t)grow * HCH + col] = h1reg[t][r] + silu_f(acc[r] + bb);
        }
    }
}

// ---------------- CSR scatter->gather pipeline (round-13, proven) ----------------
__global__ __launch_bounds__(256) void pcount_k(
    const float* __restrict__ sbf, const int* __restrict__ idx_ji,
    const float* __restrict__ w1, unsigned short* __restrict__ pB,
    int* __restrict__ counts, int T)
{
    int t = blockIdx.x * 256 + threadIdx.x;
    if (t >= T) return;
    const float* sp = sbf + (size_t)t * SBFD;
    float acc[8];
    #pragma unroll
    for (int b = 0; b < 8; ++b) acc[b] = 0.f;
    #pragma unroll
    for (int r = 0; r < 40; r += 4) {
        float4 v = *(const float4*)(sp + r);
        #pragma unroll
        for (int b = 0; b < 8; ++b)
            acc[b] += v.x * w1[r * 8 + b] + v.y * w1[(r + 1) * 8 + b]
                    + v.z * w1[(r + 2) * 8 + b] + v.w * w1[(r + 3) * 8 + b];
    }
    {
        float2 v = *(const float2*)(sp + 40);
        #pragma unroll
        for (int b = 0; b < 8; ++b)
            acc[b] += v.x * w1[40 * 8 + b] + v.y * w1[41 * 8 + b];
    }
    uint4 pk;
    pk.x = f2bf2(acc[0], acc[1]);
    pk.y = f2bf2(acc[2], acc[3]);
    pk.z = f2bf2(acc[4], acc[5]);
    pk.w = f2bf2(acc[6], acc[7]);
    *(uint4*)(pB + (size_t)t * 8) = pk;
    atomicAdd(&counts[idx_ji[t]], 1);
}

__global__ __launch_bounds__(256) void psum1_k(const int* __restrict__ counts,
                                               int* __restrict__ bsum, int E) {
    __shared__ int s[256];
    int base = blockIdx.x * 1024;
    int tid = threadIdx.x;
    int sum = 0;
    #pragma unroll
    for (int j = 0; j < 4; ++j) { int i = base + j * 256 + tid; if (i < E) sum += counts[i]; }
    s[tid] = sum; __syncthreads();
    for (int off = 128; off > 0; off >>= 1) {
        if (tid < off) s[tid] += s[tid + off];
        __syncthreads();
    }
    if (tid == 0) bsum[blockIdx.x] = s[0];
}

__global__ __launch_bounds__(512) void psum2_k(int* bsum, int G) {
    __shared__ int s[512];
    int tid = threadIdx.x;
    s[tid] = (tid < G) ? bsum[tid] : 0;
    for (int off = 1; off < 512; off <<= 1) {
        __syncthreads();
        int v = (tid >= off) ? s[tid - off] : 0;
        __syncthreads();
        s[tid] += v;
    }
    __syncthreads();
    if (tid < G) bsum[tid] = (tid == 0) ? 0 : s[tid - 1];
}

__global__ __launch_bounds__(256) void psum3_k(const int* __restrict__ counts,
                                               const int* __restrict__ bsum,
                                               int* __restrict__ start, int E) {
    __shared__ int s[256];
    int tid = threadIdx.x;
    int base = blockIdx.x * 1024 + tid * 4;
    int v[4]; int loc = 0;
    #pragma unroll
    for (int j = 0; j < 4; ++j) { v[j] = (base + j < E) ? counts[base + j] : 0; loc += v[j]; }
    s[tid] = loc;
    for (int off = 1; off < 256; off <<= 1) {
        __syncthreads();
        int t2 = (tid >= off) ? s[tid - off] : 0;
        __syncthreads();
        s[tid] += t2;
    }
    __syncthreads();
    int run = bsum[blockIdx.x] + s[tid] - loc;
    #pragma unroll
    for (int j = 0; j < 4; ++j) { if (base + j < E) start[base + j] = run; run += v[j]; }
}

// fill: materialize kj and p streams in bucket order
__global__ __launch_bounds__(256) void fill_k(
    const int* __restrict__ idx_ji, const int* __restrict__ idx_kj,
    const unsigned short* __restrict__ pB, int* __restrict__ start,
    int* __restrict__ kjs, unsigned short* __restrict__ pSort, int T)
{
    int t = blockIdx.x * 256 + threadIdx.x;
    if (t >= T) return;
    int pos = atomicAdd(&start[idx_ji[t]], 1);
    kjs[pos] = idx_kj[t];
    *(uint4*)(pSort + (size_t)pos * 8) = *(const uint4*)(pB + (size_t)t * 8);
}

// gather: sequential kjs/pSort streams; only x64b row-gather is random (L3-hot)
__global__ __launch_bounds__(256) void gather_k(
    const int* __restrict__ kjs, const unsigned short* __restrict__ pSort,
    const unsigned short* __restrict__ x64b, const int* __restrict__ start,
    const int* __restrict__ counts, const float* __restrict__ w2,
    unsigned short* __restrict__ aggB, int E)
{
    int tid = threadIdx.x;
    int wave = (blockIdx.x * 256 + tid) >> 6;
    int lane = tid & 63;
    if (wave >= E) return;

    float wcol[8];
    #pragma unroll
    for (int b = 0; b < 8; ++b) wcol[b] = w2[b * 64 + lane];

    int n = counts[wave];
    int end = start[wave];
    int i = end - n;

    float acc = 0.f;
    for (; i + 4 <= end; i += 4) {
        int k0 = kjs[i], k1 = kjs[i + 1], k2 = kjs[i + 2], k3 = kjs[i + 3];
        uint4 q0 = *(const uint4*)(pSort + (size_t)i * 8);
        uint4 q1 = *(const uint4*)(pSort + (size_t)(i + 1) * 8);
        uint4 q2 = *(const uint4*)(pSort + (size_t)(i + 2) * 8);
        uint4 q3 = *(const uint4*)(pSort + (size_t)(i + 3) * 8);
        float x0 = bf2f(x64b[(size_t)k0 * ICH + lane]);
        float x1 = bf2f(x64b[(size_t)k1 * ICH + lane]);
        float x2 = bf2f(x64b[(size_t)k2 * ICH + lane]);
        float x3 = bf2f(x64b[(size_t)k3 * ICH + lane]);
        float s0 = lo16(q0.x)*wcol[0] + hi16(q0.x)*wcol[1] + lo16(q0.y)*wcol[2] + hi16(q0.y)*wcol[3]
                 + lo16(q0.z)*wcol[4] + hi16(q0.z)*wcol[5] + lo16(q0.w)*wcol[6] + hi16(q0.w)*wcol[7];
        float s1 = lo16(q1.x)*wcol[0] + hi16(q1.x)*wcol[1] + lo16(q1.y)*wcol[2] + hi16(q1.y)*wcol[3]
                 + lo16(q1.z)*wcol[4] + hi16(q1.z)*wcol[5] + lo16(q1.w)*wcol[6] + hi16(q1.w)*wcol[7];
        float s2 = lo16(q2.x)*wcol[0] + hi16(q2.x)*wcol[1] + lo16(q2.y)*wcol[2] + hi16(q2.y)*wcol[3]
                 + lo16(q2.z)*wcol[4] + hi16(q2.z)*wcol[5] + lo16(q2.w)*wcol[6] + hi16(q2.w)*wcol[7];
        float s3 = lo16(q3.x)*wcol[0] + hi16(q3.x)*wcol[1] + lo16(q3.y)*wcol[2] + hi16(q3.y)*wcol[3]
                 + lo16(q3.z)*wcol[4] + hi16(q3.z)*wcol[5] + lo16(q3.w)*wcol[6] + hi16(q3.w)*wcol[7];
        acc += s0 * x0 + s1 * x1 + s2 * x2 + s3 * x3;
    }
    for (; i < end; ++i) {
        int kj = kjs[i];
        uint4 q = *(const uint4*)(pSort + (size_t)i * 8);
        float xv = bf2f(x64b[(size_t)kj * ICH + lane]);
        float sc = lo16(q.x)*wcol[0] + hi16(q.x)*wcol[1] + lo16(q.y)*wcol[2] + hi16(q.y)*wcol[3]
                 + lo16(q.z)*wcol[4] + hi16(q.z)*wcol[5] + lo16(q.w)*wcol[6] + hi16(q.w)*wcol[7];
        acc += sc * xv;
    }
    aggB[(size_t)wave * ICH + lane] = f2bf(acc);
}

extern "C" void kernel_launch(void* const* d_in, const int* in_sizes, int n_in,
                              void* d_out, int out_size, void* d_ws, size_t ws_size,
                              hipStream_t stream) {
    const float* x      = (const float*)d_in[0];
    const float* rbf    = (const float*)d_in[1];
    const float* sbf    = (const float*)d_in[2];
    const int*   idx_kj = (const int*)d_in[3];
    const int*   idx_ji = (const int*)d_in[4];
    const float* W_rbf1 = (const float*)d_in[5];
    const float* W_rbf2 = (const float*)d_in[6];
    const float* W_sbf1 = (const float*)d_in[7];
    const float* W_sbf2 = (const float*)d_in[8];
    const float* W_kj   = (const float*)d_in[9];
    const float* b_kj   = (const float*)d_in[10];
    const float* W_ji   = (const float*)d_in[11];
    const float* b_ji   = (const float*)d_in[12];
    const float* W_down = (const float*)d_in[13];
    const float* W_up   = (const float*)d_in[14];
    const float* resbW  = (const float*)d_in[15];
    const float* resbB  = (const float*)d_in[16];
    const float* W_lin  = (const float*)d_in[17];
    const float* b_lin  = (const float*)d_in[18];
    const float* resaW  = (const float*)d_in[19];
    const float* resaB  = (const float*)d_in[20];

    const int E = in_sizes[0] / HCH;
    const int T = in_sizes[3];
    float* out = (float*)d_out;

    // ws: wc_rbf f32[1152] | counts[E] | start[E] | bsum[512] | kjs[T] |
    //     pB u16[T*8] | pSort u16[T*8] | x64b u16[E*64] | aggB u16[E*64] |
    //     hB u16[E*192] | Wt u16[WT_TOTAL]
    float* wc_rbf = (float*)d_ws;
    int*   counts = (int*)(wc_rbf + NRAD * HCH);
    int*   start  = counts + E;
    int*   bsum   = start + E;
    int*   kjs    = bsum + 512;
    unsigned short* pB    = (unsigned short*)(kjs + T);
    unsigned short* pSort = pB + (size_t)T * 8;
    unsigned short* x64b  = pSort + (size_t)T * 8;
    unsigned short* aggB  = x64b + (size_t)E * ICH;
    unsigned short* hB    = aggB + (size_t)E * ICH;
    unsigned short* Wt    = hB + (size_t)E * HCH;

    const unsigned short* Wt_kj   = Wt;
    const unsigned short* Wt_ji   = Wt + 1 * WSEG;
    const unsigned short* Wt_lin  = Wt + 2 * WSEG;
    const unsigned short* Wt_rb0  = Wt + 3 * WSEG;   // W0, W1 at +WSEG
    const unsigned short* Wt_ra   = Wt + 5 * WSEG;   // ra0_0, ra0_1, ra1_0, ra1_1
    const unsigned short* Wt_down = Wt + WT_DOWN;
    const unsigned short* Wt_up   = Wt + WT_UP;

    const int gb128 = (E + 127) / 128;
    const int gt = (T + 255) / 256;
    const int gscan = (E + 1023) / 1024;

    wc_k<<<(NRAD * HCH + NT - 1) / NT, NT, 0, stream>>>(W_rbf1, W_rbf2, wc_rbf);
    prep_k<<<(WT_TOTAL + NT - 1) / NT, NT, 0, stream>>>(W_kj, W_ji, W_lin, resbW, resaW,
                                                        W_down, W_up, Wt);

    // CSR build + stream materialization
    hipMemsetAsync(counts, 0, (size_t)E * sizeof(int), stream);
    pcount_k<<<gt, 256, 0, stream>>>(sbf, idx_ji, W_sbf1, pB, counts, T);
    psum1_k<<<gscan, 256, 0, stream>>>(counts, bsum, E);
    psum2_k<<<1, 512, 0, stream>>>(bsum, gscan);
    psum3_k<<<gscan, 256, 0, stream>>>(counts, bsum, start, E);
    fill_k<<<gt, 256, 0, stream>>>(idx_ji, idx_kj, pB, start, kjs, pSort, T);

    // x -> x64b (bf16), B via LDS
    fused12_k<<<gb128, 512, 0, stream>>>(x, Wt_kj, b_kj, rbf, wc_rbf, Wt_down, x64b, E);
    // aggB = segment_sum(x64b[kjs] * (pSort@W_sbf2))
    gather_k<<<(E + 3) / 4, 256, 0, stream>>>(kjs, pSort, x64b, start, counts, W_sbf2, aggB, E);
    // combine + res_before + lin fused (4 phases)
    creslin_k<<<gb128, 512, 0, stream>>>(x, Wt_ji, b_ji, aggB, Wt_up,
                                         Wt_rb0, Wt_rb0 + WSEG, Wt_lin,
                                         resbB, resbB + HCH, b_lin, hB, E);
    // res_after x2 fused, fp32 out
    resres_k<<<gb128, 512, 0, stream>>>(hB, Wt_ra, resaB, out, E);
}

// Round 18
// 1866.902 us; speedup vs baseline: 1.3897x; 1.0817x over previous
//
#include <hip/hip_runtime.h>
#include <cstdint>
#include <cstddef>

#define HCH 192
#define ICH 64
#define NRAD 6
#define SBFD 42

constexpr int NT = 256;

using bfrag = __attribute__((ext_vector_type(8))) short;  // 8 bf16 (4 VGPRs)
using f32x4 = __attribute__((ext_vector_type(4))) float;

#define MFMA16(a, b, c) __builtin_amdgcn_mfma_f32_16x16x32_bf16(a, b, c, 0, 0, 0)

__device__ __forceinline__ float silu_f(float v) {
    return v / (1.0f + __expf(-v));
}

__device__ __forceinline__ unsigned short f2bf(float x) {
    union { float f; unsigned u; } v; v.f = x;
    return (unsigned short)((v.u + 0x7FFFu + ((v.u >> 16) & 1u)) >> 16);
}

__device__ __forceinline__ unsigned f2bf2(float a, float b) {
    return (unsigned)f2bf(a) | ((unsigned)f2bf(b) << 16);
}

__device__ __forceinline__ float bf2f(unsigned short u) {
    union { unsigned u; float f; } v; v.u = ((unsigned)u) << 16;
    return v.f;
}

__device__ __forceinline__ float lo16(unsigned u) {
    union { unsigned x; float f; } v; v.x = u << 16; return v.f;
}
__device__ __forceinline__ float hi16(unsigned u) {
    union { unsigned x; float f; } v; v.x = u & 0xffff0000u; return v.f;
}

__device__ __forceinline__ bfrag pack8(float4 a, float4 b) {
    bfrag r;
    r[0] = (short)f2bf(a.x); r[1] = (short)f2bf(a.y);
    r[2] = (short)f2bf(a.z); r[3] = (short)f2bf(a.w);
    r[4] = (short)f2bf(b.x); r[5] = (short)f2bf(b.y);
    r[6] = (short)f2bf(b.z); r[7] = (short)f2bf(b.w);
    return r;
}

__device__ __forceinline__ bfrag bzero() {
    bfrag r;
    #pragma unroll
    for (int i = 0; i < 8; ++i) r[i] = 0;
    return r;
}

// stage a [192][192] bf16 panel into b_s[192][200] with 512 threads (9 uint4/thread)
#define STAGE_B(SRC)                                                             \
    {                                                                            \
        _Pragma("unroll")                                                        \
        for (int it = 0; it < 9; ++it) {                                         \
            int idx = it * 512 + tid;                                            \
            int r = idx / 24, c8 = idx % 24;                                     \
            *(uint4*)&b_s[r][c8 * 8] = *(const uint4*)((SRC) + (size_t)r * HCH + c8 * 8); \
        }                                                                        \
    }
// load next-phase A-frags from t_s (own wave rows)
#define AFRAGS(DST)                                                              \
    {                                                                            \
        _Pragma("unroll")                                                        \
        for (int ks = 0; ks < 6; ++ks)                                           \
            DST[ks] = *(const bfrag*)&t_s[w * 16 + lr][ks * 32 + kq];            \
    }

// ---------------- weight prep: fp32 [K][N] -> bf16 transposed [N][K] ----------------
#define WSEG 36864
#define WT_DOWN (9 * WSEG)
#define WT_UP   (9 * WSEG + 12288)
#define WT_TOTAL (9 * WSEG + 2 * 12288)

__global__ __launch_bounds__(NT) void prep_k(
    const float* __restrict__ W_kj, const float* __restrict__ W_ji,
    const float* __restrict__ W_lin, const float* __restrict__ resbW,
    const float* __restrict__ resaW, const float* __restrict__ W_down,
    const float* __restrict__ W_up, unsigned short* __restrict__ Wt)
{
    int i = blockIdx.x * NT + threadIdx.x;
    if (i < 9 * WSEG) {
        int seg = i / WSEG, r = i % WSEG;
        int k = r / HCH, n = r % HCH;
        const float* src =
            seg == 0 ? W_kj : seg == 1 ? W_ji : seg == 2 ? W_lin :
            seg <= 4 ? resbW + (seg - 3) * WSEG : resaW + (seg - 5) * WSEG;
        Wt[seg * WSEG + n * HCH + k] = f2bf(src[r]);
    } else if (i < WT_DOWN + 12288) {
        int r = i - WT_DOWN;
        int k = r / ICH, n = r % ICH;           // W_down [192][64]
        Wt[WT_DOWN + n * HCH + k] = f2bf(W_down[r]);
    } else if (i < WT_TOTAL) {
        int r = i - WT_UP;
        int k = r / HCH, n = r % HCH;           // W_up [64][192]
        Wt[WT_UP + n * ICH + k] = f2bf(W_up[r]);
    }
}

// wc_rbf[6,192] = W_rbf1[6,8] @ W_rbf2[8,192]  (kept fp32)
__global__ void wc_k(const float* __restrict__ W_rbf1, const float* __restrict__ W_rbf2,
                     float* __restrict__ wc)
{
    int tid = blockIdx.x * blockDim.x + threadIdx.x;
    if (tid < NRAD * HCH) {
        int r = tid / HCH, c = tid % HCH;
        float a = 0.f;
        #pragma unroll
        for (int b = 0; b < 8; ++b) a += W_rbf1[r * 8 + b] * W_rbf2[b * HCH + c];
        wc[tid] = a;
    }
}

// ---------------- head: x -> x64b (bf16), B staged in LDS (round-13, proven) ----------------
__global__ __launch_bounds__(512) void fused12_k(
    const float* __restrict__ x, const unsigned short* __restrict__ Wt_kj,
    const float* __restrict__ b_kj, const float* __restrict__ rbf,
    const float* __restrict__ wc, const unsigned short* __restrict__ Wt_down,
    unsigned short* __restrict__ x64b, int E)
{
    __shared__ unsigned short b_s[192][200];
    __shared__ unsigned short u_s[128][200];
    __shared__ float wc_s[NRAD * HCH];
    const int tid = threadIdx.x;
    const int lane = tid & 63, w = tid >> 6;
    const int row0 = blockIdx.x * 128;
    const int lr = lane & 15, lq = lane >> 4;
    const int kq = lq * 8;
    const int ra = row0 + w * 16 + lr;
    const bool rav = ra < E;

    STAGE_B(Wt_kj);
    for (int i = tid; i < NRAD * HCH; i += 512) wc_s[i] = wc[i];

    bfrag a[6];
    #pragma unroll
    for (int ks = 0; ks < 6; ++ks) {
        float4 a0 = make_float4(0,0,0,0), a1 = make_float4(0,0,0,0);
        if (rav) {
            a0 = *(const float4*)(x + (size_t)ra * HCH + ks * 32 + kq);
            a1 = *(const float4*)(x + (size_t)ra * HCH + ks * 32 + kq + 4);
        }
        a[ks] = pack8(a0, a1);
    }
    float rb[4][NRAD];
    #pragma unroll
    for (int r = 0; r < 4; ++r) {
        int grow = row0 + w * 16 + lq * 4 + r;
        #pragma unroll
        for (int q = 0; q < NRAD; ++q)
            rb[r][q] = (grow < E) ? rbf[(size_t)grow * NRAD + q] : 0.f;
    }
    __syncthreads();

    #pragma unroll
    for (int t = 0; t < 12; ++t) {
        f32x4 acc = (f32x4){0.f, 0.f, 0.f, 0.f};
        #pragma unroll
        for (int ks = 0; ks < 6; ++ks) {
            bfrag b = *(const bfrag*)&b_s[t * 16 + lr][ks * 32 + kq];
            acc = MFMA16(a[ks], b, acc);
        }
        int col = t * 16 + lr;
        float bb = b_kj[col];
        #pragma unroll
        for (int r = 0; r < 4; ++r) {
            float sv = silu_f(acc[r] + bb);
            float rh = 0.f;
            #pragma unroll
            for (int q = 0; q < NRAD; ++q) rh += rb[r][q] * wc_s[q * HCH + col];
            u_s[w * 16 + lq * 4 + r][col] = f2bf(sv * rh);
        }
    }
    __syncthreads();

    #pragma unroll
    for (int it = 0; it < 3; ++it) {
        int idx = it * 512 + tid;
        int r = idx / 24, c8 = idx % 24;
        *(uint4*)&b_s[r][c8 * 8] = *(const uint4*)(Wt_down + (size_t)r * HCH + c8 * 8);
    }
    bfrag a2[6];
    #pragma unroll
    for (int ks = 0; ks < 6; ++ks)
        a2[ks] = *(const bfrag*)&u_s[w * 16 + lr][ks * 32 + kq];
    __syncthreads();

    float o[4][4];
    #pragma unroll
    for (int t = 0; t < 4; ++t) {
        f32x4 acc = (f32x4){0.f, 0.f, 0.f, 0.f};
        #pragma unroll
        for (int ks = 0; ks < 6; ++ks) {
            bfrag b = *(const bfrag*)&b_s[t * 16 + lr][ks * 32 + kq];
            acc = MFMA16(a2[ks], b, acc);
        }
        #pragma unroll
        for (int r = 0; r < 4; ++r) o[t][r] = silu_f(acc[r]);
    }
    __syncthreads();
    #pragma unroll
    for (int t = 0; t < 4; ++t)
        #pragma unroll
        for (int r = 0; r < 4; ++r)
            u_s[w * 16 + lq * 4 + r][t * 16 + lr] = f2bf(o[t][r]);
    __syncthreads();

    #pragma unroll
    for (int it = 0; it < 2; ++it) {
        int idx = it * 512 + tid;
        int r = idx >> 3, c8 = (idx & 7) * 8;
        int grow = row0 + r;
        if (grow < E)
            *(uint4*)(x64b + (size_t)grow * ICH + c8) = *(const uint4*)&u_s[r][c8];
    }
}

// ---------------- fully fused tail: combine + res_b0 + lin + res_a0 + res_a1 ----------------
// 8 GEMM phases; residual carry lives in hreg (fp32 registers), activations
// bounce via t_s (wave-private rows). out written fp32 at the end.
__global__ __launch_bounds__(512) void treslin_k(
    const float* __restrict__ x, const unsigned short* __restrict__ Wt_ji,
    const float* __restrict__ b_ji, const unsigned short* __restrict__ aggB,
    const unsigned short* __restrict__ Wt_up,
    const unsigned short* __restrict__ Wt_rb,   // W0, W1 (+WSEG)
    const unsigned short* __restrict__ Wt_lin,
    const unsigned short* __restrict__ Wt_ra,   // 4 panels
    const float* __restrict__ rbB,              // [2][192]
    const float* __restrict__ b_lin,
    const float* __restrict__ raB,              // [4][192]
    float* __restrict__ out, int E)
{
    __shared__ unsigned short b_s[192][200];   // 76.8 KB
    __shared__ unsigned short t_s[128][200];   // 51.2 KB (wave-private rows)
    __shared__ unsigned short bu_s[192][72];   // 27.6 KB (W_up, P0 only)
    const int tid = threadIdx.x;
    const int lane = tid & 63, w = tid >> 6;
    const int row0 = blockIdx.x * 128;
    const int lr = lane & 15, lq = lane >> 4;
    const int kq = lq * 8;
    const int ra = row0 + w * 16 + lr;
    const bool rav = ra < E;

    STAGE_B(Wt_ji);
    #pragma unroll
    for (int it = 0; it < 3; ++it) {
        int idx = it * 512 + tid;
        int r = idx / 8, c8 = idx % 8;
        *(uint4*)&bu_s[r][c8 * 8] = *(const uint4*)(Wt_up + (size_t)r * ICH + c8 * 8);
    }

    bfrag aag[2], af[6];
    #pragma unroll
    for (int ks = 0; ks < 2; ++ks)
        aag[ks] = rav ? *(const bfrag*)(aggB + (size_t)ra * ICH + ks * 32 + kq) : bzero();
    #pragma unroll
    for (int ks = 0; ks < 6; ++ks) {
        float4 a0 = make_float4(0,0,0,0), a1 = make_float4(0,0,0,0);
        if (rav) {
            a0 = *(const float4*)(x + (size_t)ra * HCH + ks * 32 + kq);
            a1 = *(const float4*)(x + (size_t)ra * HCH + ks * 32 + kq + 4);
        }
        af[ks] = pack8(a0, a1);
    }
    __syncthreads();

    // P0: h = silu(x@W_ji + b_ji) + silu(agg@W_up); fp32 -> hreg, bf16 -> t_s
    float hreg[12][4];
    #pragma unroll
    for (int t = 0; t < 12; ++t) {
        f32x4 au = (f32x4){0.f, 0.f, 0.f, 0.f};
        #pragma unroll
        for (int ks = 0; ks < 2; ++ks) {
            bfrag bu = *(const bfrag*)&bu_s[t * 16 + lr][ks * 32 + kq];
            au = MFMA16(aag[ks], bu, au);
        }
        f32x4 aj = (f32x4){0.f, 0.f, 0.f, 0.f};
        #pragma unroll
        for (int ks = 0; ks < 6; ++ks) {
            bfrag b = *(const bfrag*)&b_s[t * 16 + lr][ks * 32 + kq];
            aj = MFMA16(af[ks], b, aj);
        }
        int col = t * 16 + lr;
        float bb = b_ji[col];
        #pragma unroll
        for (int r = 0; r < 4; ++r) {
            float h = silu_f(aj[r] + bb) + silu_f(au[r]);
            hreg[t][r] = h;
            t_s[w * 16 + lq * 4 + r][col] = f2bf(h);
        }
    }
    __syncthreads();

    // P1: t = silu(h@W0 + b0)
    STAGE_B(Wt_rb);
    AFRAGS(af);
    __syncthreads();
    #pragma unroll
    for (int t = 0; t < 12; ++t) {
        f32x4 acc = (f32x4){0.f, 0.f, 0.f, 0.f};
        #pragma unroll
        for (int ks = 0; ks < 6; ++ks) {
            bfrag b = *(const bfrag*)&b_s[t * 16 + lr][ks * 32 + kq];
            acc = MFMA16(af[ks], b, acc);
        }
        int col = t * 16 + lr;
        float bb = rbB[col];
        #pragma unroll
        for (int r = 0; r < 4; ++r)
            t_s[w * 16 + lq * 4 + r][col] = f2bf(silu_f(acc[r] + bb));
    }
    __syncthreads();

    // P2: h1 = hreg + silu(t@W1 + b1) -> hreg, t_s
    STAGE_B(Wt_rb + WSEG);
    AFRAGS(af);
    __syncthreads();
    #pragma unroll
    for (int t = 0; t < 12; ++t) {
        f32x4 acc = (f32x4){0.f, 0.f, 0.f, 0.f};
        #pragma unroll
        for (int ks = 0; ks < 6; ++ks) {
            bfrag b = *(const bfrag*)&b_s[t * 16 + lr][ks * 32 + kq];
            acc = MFMA16(af[ks], b, acc);
        }
        int col = t * 16 + lr;
        float bb = rbB[HCH + col];
        #pragma unroll
        for (int r = 0; r < 4; ++r) {
            float h1 = hreg[t][r] + silu_f(acc[r] + bb);
            hreg[t][r] = h1;
            t_s[w * 16 + lq * 4 + r][col] = f2bf(h1);
        }
    }
    __syncthreads();

    // P3: h2 = silu(h1@W_lin + b_lin) + x -> hreg, t_s
    STAGE_B(Wt_lin);
    AFRAGS(af);
    __syncthreads();
    #pragma unroll
    for (int t = 0; t < 12; ++t) {
        f32x4 acc = (f32x4){0.f, 0.f, 0.f, 0.f};
        #pragma unroll
        for (int ks = 0; ks < 6; ++ks) {
            bfrag b = *(const bfrag*)&b_s[t * 16 + lr][ks * 32 + kq];
            acc = MFMA16(af[ks], b, acc);
        }
        int col = t * 16 + lr;
        float bb = b_lin[col];
        #pragma unroll
        for (int r = 0; r < 4; ++r) {
            int grow = row0 + w * 16 + lq * 4 + r;
            float xv = (grow < E) ? x[(size_t)grow * HCH + col] : 0.f;
            float h2 = silu_f(acc[r] + bb) + xv;
            hreg[t][r] = h2;
            t_s[w * 16 + lq * 4 + r][col] = f2bf(h2);
        }
    }
    __syncthreads();

    // P4: t = silu(h2@Wra0_0 + raB0)
    STAGE_B(Wt_ra);
    AFRAGS(af);
    __syncthreads();
    #pragma unroll
    for (int t = 0; t < 12; ++t) {
        f32x4 acc = (f32x4){0.f, 0.f, 0.f, 0.f};
        #pragma unroll
        for (int ks = 0; ks < 6; ++ks) {
            bfrag b = *(const bfrag*)&b_s[t * 16 + lr][ks * 32 + kq];
            acc = MFMA16(af[ks], b, acc);
        }
        int col = t * 16 + lr;
        float bb = raB[col];
        #pragma unroll
        for (int r = 0; r < 4; ++r)
            t_s[w * 16 + lq * 4 + r][col] = f2bf(silu_f(acc[r] + bb));
    }
    __syncthreads();

    // P5: h3 = hreg + silu(t@Wra0_1 + raB1) -> hreg, t_s
    STAGE_B(Wt_ra + WSEG);
    AFRAGS(af);
    __syncthreads();
    #pragma unroll
    for (int t = 0; t < 12; ++t) {
        f32x4 acc = (f32x4){0.f, 0.f, 0.f, 0.f};
        #pragma unroll
        for (int ks = 0; ks < 6; ++ks) {
            bfrag b = *(const bfrag*)&b_s[t * 16 + lr][ks * 32 + kq];
            acc = MFMA16(af[ks], b, acc);
        }
        int col = t * 16 + lr;
        float bb = raB[HCH + col];
        #pragma unroll
        for (int r = 0; r < 4; ++r) {
            float h3 = hreg[t][r] + silu_f(acc[r] + bb);
            hreg[t][r] = h3;
            t_s[w * 16 + lq * 4 + r][col] = f2bf(h3);
        }
    }
    __syncthreads();

    // P6: t = silu(h3@Wra1_0 + raB2)
    STAGE_B(Wt_ra + 2 * WSEG);
    AFRAGS(af);
    __syncthreads();
    #pragma unroll
    for (int t = 0; t < 12; ++t) {
        f32x4 acc = (f32x4){0.f, 0.f, 0.f, 0.f};
        #pragma unroll
        for (int ks = 0; ks < 6; ++ks) {
            bfrag b = *(const bfrag*)&b_s[t * 16 + lr][ks * 32 + kq];
            acc = MFMA16(af[ks], b, acc);
        }
        int col = t * 16 + lr;
        float bb = raB[2 * HCH + col];
        #pragma unroll
        for (int r = 0; r < 4; ++r)
            t_s[w * 16 + lq * 4 + r][col] = f2bf(silu_f(acc[r] + bb));
    }
    __syncthreads();

    // P7: out = hreg + silu(t@Wra1_1 + raB3)  (fp32 out)
    STAGE_B(Wt_ra + 3 * WSEG);
    AFRAGS(af);
    __syncthreads();
    #pragma unroll
    for (int t = 0; t < 12; ++t) {
        f32x4 acc = (f32x4){0.f, 0.f, 0.f, 0.f};
        #pragma unroll
        for (int ks = 0; ks < 6; ++ks) {
            bfrag b = *(const bfrag*)&b_s[t * 16 + lr][ks * 32 + kq];
            acc = MFMA16(af[ks], b, acc);
        }
        int col = t * 16 + lr;
        float bb = raB[3 * HCH + col];
        #pragma unroll
        for (int r = 0; r < 4; ++r) {
            int grow = row0 + w * 16 + lq * 4 + r;
            if (grow >= E) continue;
            out[(size_t)grow * HCH + col] = hreg[t][r] + silu_f(acc[r] + bb);
        }
    }
}

// ---------------- CSR scatter->gather pipeline (round-13, proven) ----------------
__global__ __launch_bounds__(256) void pcount_k(
    const float* __restrict__ sbf, const int* __restrict__ idx_ji,
    const float* __restrict__ w1, unsigned short* __restrict__ pB,
    int* __restrict__ counts, int T)
{
    int t = blockIdx.x * 256 + threadIdx.x;
    if (t >= T) return;
    const float* sp = sbf + (size_t)t * SBFD;
    float acc[8];
    #pragma unroll
    for (int b = 0; b < 8; ++b) acc[b] = 0.f;
    #pragma unroll
    for (int r = 0; r < 40; r += 4) {
        float4 v = *(const float4*)(sp + r);
        #pragma unroll
        for (int b = 0; b < 8; ++b)
            acc[b] += v.x * w1[r * 8 + b] + v.y * w1[(r + 1) * 8 + b]
                    + v.z * w1[(r + 2) * 8 + b] + v.w * w1[(r + 3) * 8 + b];
    }
    {
        float2 v = *(const float2*)(sp + 40);
        #pragma unroll
        for (int b = 0; b < 8; ++b)
            acc[b] += v.x * w1[40 * 8 + b] + v.y * w1[41 * 8 + b];
    }
    uint4 pk;
    pk.x = f2bf2(acc[0], acc[1]);
    pk.y = f2bf2(acc[2], acc[3]);
    pk.z = f2bf2(acc[4], acc[5]);
    pk.w = f2bf2(acc[6], acc[7]);
    *(uint4*)(pB + (size_t)t * 8) = pk;
    atomicAdd(&counts[idx_ji[t]], 1);
}

__global__ __launch_bounds__(256) void psum1_k(const int* __restrict__ counts,
                                               int* __restrict__ bsum, int E) {
    __shared__ int s[256];
    int base = blockIdx.x * 1024;
    int tid = threadIdx.x;
    int sum = 0;
    #pragma unroll
    for (int j = 0; j < 4; ++j) { int i = base + j * 256 + tid; if (i < E) sum += counts[i]; }
    s[tid] = sum; __syncthreads();
    for (int off = 128; off > 0; off >>= 1) {
        if (tid < off) s[tid] += s[tid + off];
        __syncthreads();
    }
    if (tid == 0) bsum[blockIdx.x] = s[0];
}

__global__ __launch_bounds__(512) void psum2_k(int* bsum, int G) {
    __shared__ int s[512];
    int tid = threadIdx.x;
    s[tid] = (tid < G) ? bsum[tid] : 0;
    for (int off = 1; off < 512; off <<= 1) {
        __syncthreads();
        int v = (tid >= off) ? s[tid - off] : 0;
        __syncthreads();
        s[tid] += v;
    }
    __syncthreads();
    if (tid < G) bsum[tid] = (tid == 0) ? 0 : s[tid - 1];
}

__global__ __launch_bounds__(256) void psum3_k(const int* __restrict__ counts,
                                               const int* __restrict__ bsum,
                                               int* __restrict__ start, int E) {
    __shared__ int s[256];
    int tid = threadIdx.x;
    int base = blockIdx.x * 1024 + tid * 4;
    int v[4]; int loc = 0;
    #pragma unroll
    for (int j = 0; j < 4; ++j) { v[j] = (base + j < E) ? counts[base + j] : 0; loc += v[j]; }
    s[tid] = loc;
    for (int off = 1; off < 256; off <<= 1) {
        __syncthreads();
        int t2 = (tid >= off) ? s[tid - off] : 0;
        __syncthreads();
        s[tid] += t2;
    }
    __syncthreads();
    int run = bsum[blockIdx.x] + s[tid] - loc;
    #pragma unroll
    for (int j = 0; j < 4; ++j) { if (base + j < E) start[base + j] = run; run += v[j]; }
}

// fill: materialize kj and p streams in bucket order
__global__ __launch_bounds__(256) void fill_k(
    const int* __restrict__ idx_ji, const int* __restrict__ idx_kj,
    const unsigned short* __restrict__ pB, int* __restrict__ start,
    int* __restrict__ kjs, unsigned short* __restrict__ pSort, int T)
{
    int t = blockIdx.x * 256 + threadIdx.x;
    if (t >= T) return;
    int pos = atomicAdd(&start[idx_ji[t]], 1);
    kjs[pos] = idx_kj[t];
    *(uint4*)(pSort + (size_t)pos * 8) = *(const uint4*)(pB + (size_t)t * 8);
}

// gather: sequential kjs/pSort streams; only x64b row-gather is random (L3-hot)
__global__ __launch_bounds__(256) void gather_k(
    const int* __restrict__ kjs, const unsigned short* __restrict__ pSort,
    const unsigned short* __restrict__ x64b, const int* __restrict__ start,
    const int* __restrict__ counts, const float* __restrict__ w2,
    unsigned short* __restrict__ aggB, int E)
{
    int tid = threadIdx.x;
    int wave = (blockIdx.x * 256 + tid) >> 6;
    int lane = tid & 63;
    if (wave >= E) return;

    float wcol[8];
    #pragma unroll
    for (int b = 0; b < 8; ++b) wcol[b] = w2[b * 64 + lane];

    int n = counts[wave];
    int end = start[wave];
    int i = end - n;

    float acc = 0.f;
    for (; i + 4 <= end; i += 4) {
        int k0 = kjs[i], k1 = kjs[i + 1], k2 = kjs[i + 2], k3 = kjs[i + 3];
        uint4 q0 = *(const uint4*)(pSort + (size_t)i * 8);
        uint4 q1 = *(const uint4*)(pSort + (size_t)(i + 1) * 8);
        uint4 q2 = *(const uint4*)(pSort + (size_t)(i + 2) * 8);
        uint4 q3 = *(const uint4*)(pSort + (size_t)(i + 3) * 8);
        float x0 = bf2f(x64b[(size_t)k0 * ICH + lane]);
        float x1 = bf2f(x64b[(size_t)k1 * ICH + lane]);
        float x2 = bf2f(x64b[(size_t)k2 * ICH + lane]);
        float x3 = bf2f(x64b[(size_t)k3 * ICH + lane]);
        float s0 = lo16(q0.x)*wcol[0] + hi16(q0.x)*wcol[1] + lo16(q0.y)*wcol[2] + hi16(q0.y)*wcol[3]
                 + lo16(q0.z)*wcol[4] + hi16(q0.z)*wcol[5] + lo16(q0.w)*wcol[6] + hi16(q0.w)*wcol[7];
        float s1 = lo16(q1.x)*wcol[0] + hi16(q1.x)*wcol[1] + lo16(q1.y)*wcol[2] + hi16(q1.y)*wcol[3]
                 + lo16(q1.z)*wcol[4] + hi16(q1.z)*wcol[5] + lo16(q1.w)*wcol[6] + hi16(q1.w)*wcol[7];
        float s2 = lo16(q2.x)*wcol[0] + hi16(q2.x)*wcol[1] + lo16(q2.y)*wcol[2] + hi16(q2.y)*wcol[3]
                 + lo16(q2.z)*wcol[4] + hi16(q2.z)*wcol[5] + lo16(q2.w)*wcol[6] + hi16(q2.w)*wcol[7];
        float s3 = lo16(q3.x)*wcol[0] + hi16(q3.x)*wcol[1] + lo16(q3.y)*wcol[2] + hi16(q3.y)*wcol[3]
                 + lo16(q3.z)*wcol[4] + hi16(q3.z)*wcol[5] + lo16(q3.w)*wcol[6] + hi16(q3.w)*wcol[7];
        acc += s0 * x0 + s1 * x1 + s2 * x2 + s3 * x3;
    }
    for (; i < end; ++i) {
        int kj = kjs[i];
        uint4 q = *(const uint4*)(pSort + (size_t)i * 8);
        float xv = bf2f(x64b[(size_t)kj * ICH + lane]);
        float sc = lo16(q.x)*wcol[0] + hi16(q.x)*wcol[1] + lo16(q.y)*wcol[2] + hi16(q.y)*wcol[3]
                 + lo16(q.z)*wcol[4] + hi16(q.z)*wcol[5] + lo16(q.w)*wcol[6] + hi16(q.w)*wcol[7];
        acc += sc * xv;
    }
    aggB[(size_t)wave * ICH + lane] = f2bf(acc);
}

extern "C" void kernel_launch(void* const* d_in, const int* in_sizes, int n_in,
                              void* d_out, int out_size, void* d_ws, size_t ws_size,
                              hipStream_t stream) {
    const float* x      = (const float*)d_in[0];
    const float* rbf    = (const float*)d_in[1];
    const float* sbf    = (const float*)d_in[2];
    const int*   idx_kj = (const int*)d_in[3];
    const int*   idx_ji = (const int*)d_in[4];
    const float* W_rbf1 = (const float*)d_in[5];
    const float* W_rbf2 = (const float*)d_in[6];
    const float* W_sbf1 = (const float*)d_in[7];
    const float* W_sbf2 = (const float*)d_in[8];
    const float* W_kj   = (const float*)d_in[9];
    const float* b_kj   = (const float*)d_in[10];
    const float* W_ji   = (const float*)d_in[11];
    const float* b_ji   = (const float*)d_in[12];
    const float* W_down = (const float*)d_in[13];
    const float* W_up   = (const float*)d_in[14];
    const float* resbW  = (const float*)d_in[15];
    const float* resbB  = (const float*)d_in[16];
    const float* W_lin  = (const float*)d_in[17];
    const float* b_lin  = (const float*)d_in[18];
    const float* resaW  = (const float*)d_in[19];
    const float* resaB  = (const float*)d_in[20];

    const int E = in_sizes[0] / HCH;
    const int T = in_sizes[3];
    float* out = (float*)d_out;

    // ws: wc_rbf f32[1152] | counts[E] | start[E] | bsum[512] | kjs[T] |
    //     pB u16[T*8] | pSort u16[T*8] | x64b u16[E*64] | aggB u16[E*64] |
    //     Wt u16[WT_TOTAL]
    float* wc_rbf = (float*)d_ws;
    int*   counts = (int*)(wc_rbf + NRAD * HCH);
    int*   start  = counts + E;
    int*   bsum   = start + E;
    int*   kjs    = bsum + 512;
    unsigned short* pB    = (unsigned short*)(kjs + T);
    unsigned short* pSort = pB + (size_t)T * 8;
    unsigned short* x64b  = pSort + (size_t)T * 8;
    unsigned short* aggB  = x64b + (size_t)E * ICH;
    unsigned short* Wt    = aggB + (size_t)E * ICH;

    const unsigned short* Wt_kj   = Wt;
    const unsigned short* Wt_ji   = Wt + 1 * WSEG;
    const unsigned short* Wt_lin  = Wt + 2 * WSEG;
    const unsigned short* Wt_rb0  = Wt + 3 * WSEG;   // W0, W1 at +WSEG
    const unsigned short* Wt_ra   = Wt + 5 * WSEG;   // ra0_0, ra0_1, ra1_0, ra1_1
    const unsigned short* Wt_down = Wt + WT_DOWN;
    const unsigned short* Wt_up   = Wt + WT_UP;

    const int gb128 = (E + 127) / 128;
    const int gt = (T + 255) / 256;
    const int gscan = (E + 1023) / 1024;

    wc_k<<<(NRAD * HCH + NT - 1) / NT, NT, 0, stream>>>(W_rbf1, W_rbf2, wc_rbf);
    prep_k<<<(WT_TOTAL + NT - 1) / NT, NT, 0, stream>>>(W_kj, W_ji, W_lin, resbW, resaW,
                                                        W_down, W_up, Wt);

    // CSR build + stream materialization
    hipMemsetAsync(counts, 0, (size_t)E * sizeof(int), stream);
    pcount_k<<<gt, 256, 0, stream>>>(sbf, idx_ji, W_sbf1, pB, counts, T);
    psum1_k<<<gscan, 256, 0, stream>>>(counts, bsum, E);
    psum2_k<<<1, 512, 0, stream>>>(bsum, gscan);
    psum3_k<<<gscan, 256, 0, stream>>>(counts, bsum, start, E);
    fill_k<<<gt, 256, 0, stream>>>(idx_ji, idx_kj, pB, start, kjs, pSort, T);

    // x -> x64b (bf16), B via LDS
    fused12_k<<<gb128, 512, 0, stream>>>(x, Wt_kj, b_kj, rbf, wc_rbf, Wt_down, x64b, E);
    // aggB = segment_sum(x64b[kjs] * (pSort@W_sbf2))
    gather_k<<<(E + 3) / 4, 256, 0, stream>>>(kjs, pSort, x64b, start, counts, W_sbf2, aggB, E);
    // fully fused tail: combine + res_b0 + lin + res_a0 + res_a1, fp32 out
    treslin_k<<<gb128, 512, 0, stream>>>(x, Wt_ji, b_ji, aggB, Wt_up,
                                         Wt_rb0, Wt_lin, Wt_ra,
                                         resbB, b_lin, resaB, out, E);
}

// Round 19
// 1681.911 us; speedup vs baseline: 1.5426x; 1.1100x over previous
//
#include <hip/hip_runtime.h>
#include <cstdint>
#include <cstddef>

#define HCH 192
#define ICH 64
#define NRAD 6
#define SBFD 42

constexpr int NT = 256;

using bfrag = __attribute__((ext_vector_type(8))) short;  // 8 bf16 (4 VGPRs)
using f32x4 = __attribute__((ext_vector_type(4))) float;

#define MFMA16(a, b, c) __builtin_amdgcn_mfma_f32_16x16x32_bf16(a, b, c, 0, 0, 0)

// fast silu: raw v_rcp_f32 (1 ulp) instead of precise division sequence
__device__ __forceinline__ float silu_f(float v) {
    return v * __builtin_amdgcn_rcpf(1.0f + __expf(-v));
}

__device__ __forceinline__ unsigned short f2bf(float x) {
    union { float f; unsigned u; } v; v.f = x;
    return (unsigned short)((v.u + 0x7FFFu + ((v.u >> 16) & 1u)) >> 16);
}

__device__ __forceinline__ unsigned f2bf2(float a, float b) {
    return (unsigned)f2bf(a) | ((unsigned)f2bf(b) << 16);
}

__device__ __forceinline__ float bf2f(unsigned short u) {
    union { unsigned u; float f; } v; v.u = ((unsigned)u) << 16;
    return v.f;
}

__device__ __forceinline__ float lo16(unsigned u) {
    union { unsigned x; float f; } v; v.x = u << 16; return v.f;
}
__device__ __forceinline__ float hi16(unsigned u) {
    union { unsigned x; float f; } v; v.x = u & 0xffff0000u; return v.f;
}

__device__ __forceinline__ bfrag pack8(float4 a, float4 b) {
    bfrag r;
    r[0] = (short)f2bf(a.x); r[1] = (short)f2bf(a.y);
    r[2] = (short)f2bf(a.z); r[3] = (short)f2bf(a.w);
    r[4] = (short)f2bf(b.x); r[5] = (short)f2bf(b.y);
    r[6] = (short)f2bf(b.z); r[7] = (short)f2bf(b.w);
    return r;
}

__device__ __forceinline__ bfrag bzero() {
    bfrag r;
    #pragma unroll
    for (int i = 0; i < 8; ++i) r[i] = 0;
    return r;
}

// stage a [192][192] bf16 panel into b_s[192][200] with 512 threads (9 uint4/thread)
#define STAGE_B(SRC)                                                             \
    {                                                                            \
        _Pragma("unroll")                                                        \
        for (int it = 0; it < 9; ++it) {                                         \
            int idx = it * 512 + tid;                                            \
            int r = idx / 24, c8 = idx % 24;                                     \
            *(uint4*)&b_s[r][c8 * 8] = *(const uint4*)((SRC) + (size_t)r * HCH + c8 * 8); \
        }                                                                        \
    }
// load next-phase A-frags from t_s (own wave rows)
#define AFRAGS(DST)                                                              \
    {                                                                            \
        _Pragma("unroll")                                                        \
        for (int ks = 0; ks < 6; ++ks)                                           \
            DST[ks] = *(const bfrag*)&t_s[w * 16 + lr][ks * 32 + kq];            \
    }

// ---------------- weight prep: fp32 [K][N] -> bf16 transposed [N][K] ----------------
#define WSEG 36864
#define WT_DOWN (9 * WSEG)
#define WT_UP   (9 * WSEG + 12288)
#define WT_TOTAL (9 * WSEG + 2 * 12288)

__global__ __launch_bounds__(NT) void prep_k(
    const float* __restrict__ W_kj, const float* __restrict__ W_ji,
    const float* __restrict__ W_lin, const float* __restrict__ resbW,
    const float* __restrict__ resaW, const float* __restrict__ W_down,
    const float* __restrict__ W_up, unsigned short* __restrict__ Wt)
{
    int i = blockIdx.x * NT + threadIdx.x;
    if (i < 9 * WSEG) {
        int seg = i / WSEG, r = i % WSEG;
        int k = r / HCH, n = r % HCH;
        const float* src =
            seg == 0 ? W_kj : seg == 1 ? W_ji : seg == 2 ? W_lin :
            seg <= 4 ? resbW + (seg - 3) * WSEG : resaW + (seg - 5) * WSEG;
        Wt[seg * WSEG + n * HCH + k] = f2bf(src[r]);
    } else if (i < WT_DOWN + 12288) {
        int r = i - WT_DOWN;
        int k = r / ICH, n = r % ICH;           // W_down [192][64]
        Wt[WT_DOWN + n * HCH + k] = f2bf(W_down[r]);
    } else if (i < WT_TOTAL) {
        int r = i - WT_UP;
        int k = r / HCH, n = r % HCH;           // W_up [64][192]
        Wt[WT_UP + n * ICH + k] = f2bf(W_up[r]);
    }
}

// wc_rbf[6,192] = W_rbf1[6,8] @ W_rbf2[8,192]  (kept fp32)
__global__ void wc_k(const float* __restrict__ W_rbf1, const float* __restrict__ W_rbf2,
                     float* __restrict__ wc)
{
    int tid = blockIdx.x * blockDim.x + threadIdx.x;
    if (tid < NRAD * HCH) {
        int r = tid / HCH, c = tid % HCH;
        float a = 0.f;
        #pragma unroll
        for (int b = 0; b < 8; ++b) a += W_rbf1[r * 8 + b] * W_rbf2[b * HCH + c];
        wc[tid] = a;
    }
}

// ---------------- head: x -> x64b (bf16), B staged in LDS (round-13, proven) ----------------
__global__ __launch_bounds__(512) void fused12_k(
    const float* __restrict__ x, const unsigned short* __restrict__ Wt_kj,
    const float* __restrict__ b_kj, const float* __restrict__ rbf,
    const float* __restrict__ wc, const unsigned short* __restrict__ Wt_down,
    unsigned short* __restrict__ x64b, int E)
{
    __shared__ unsigned short b_s[192][200];
    __shared__ unsigned short u_s[128][200];
    __shared__ float wc_s[NRAD * HCH];
    const int tid = threadIdx.x;
    const int lane = tid & 63, w = tid >> 6;
    const int row0 = blockIdx.x * 128;
    const int lr = lane & 15, lq = lane >> 4;
    const int kq = lq * 8;
    const int ra = row0 + w * 16 + lr;
    const bool rav = ra < E;

    STAGE_B(Wt_kj);
    for (int i = tid; i < NRAD * HCH; i += 512) wc_s[i] = wc[i];

    bfrag a[6];
    #pragma unroll
    for (int ks = 0; ks < 6; ++ks) {
        float4 a0 = make_float4(0,0,0,0), a1 = make_float4(0,0,0,0);
        if (rav) {
            a0 = *(const float4*)(x + (size_t)ra * HCH + ks * 32 + kq);
            a1 = *(const float4*)(x + (size_t)ra * HCH + ks * 32 + kq + 4);
        }
        a[ks] = pack8(a0, a1);
    }
    float rb[4][NRAD];
    #pragma unroll
    for (int r = 0; r < 4; ++r) {
        int grow = row0 + w * 16 + lq * 4 + r;
        #pragma unroll
        for (int q = 0; q < NRAD; ++q)
            rb[r][q] = (grow < E) ? rbf[(size_t)grow * NRAD + q] : 0.f;
    }
    __syncthreads();

    #pragma unroll
    for (int t = 0; t < 12; ++t) {
        f32x4 acc = (f32x4){0.f, 0.f, 0.f, 0.f};
        #pragma unroll
        for (int ks = 0; ks < 6; ++ks) {
            bfrag b = *(const bfrag*)&b_s[t * 16 + lr][ks * 32 + kq];
            acc = MFMA16(a[ks], b, acc);
        }
        int col = t * 16 + lr;
        float bb = b_kj[col];
        #pragma unroll
        for (int r = 0; r < 4; ++r) {
            float sv = silu_f(acc[r] + bb);
            float rh = 0.f;
            #pragma unroll
            for (int q = 0; q < NRAD; ++q) rh += rb[r][q] * wc_s[q * HCH + col];
            u_s[w * 16 + lq * 4 + r][col] = f2bf(sv * rh);
        }
    }
    __syncthreads();

    #pragma unroll
    for (int it = 0; it < 3; ++it) {
        int idx = it * 512 + tid;
        int r = idx / 24, c8 = idx % 24;
        *(uint4*)&b_s[r][c8 * 8] = *(const uint4*)(Wt_down + (size_t)r * HCH + c8 * 8);
    }
    bfrag a2[6];
    #pragma unroll
    for (int ks = 0; ks < 6; ++ks)
        a2[ks] = *(const bfrag*)&u_s[w * 16 + lr][ks * 32 + kq];
    __syncthreads();

    float o[4][4];
    #pragma unroll
    for (int t = 0; t < 4; ++t) {
        f32x4 acc = (f32x4){0.f, 0.f, 0.f, 0.f};
        #pragma unroll
        for (int ks = 0; ks < 6; ++ks) {
            bfrag b = *(const bfrag*)&b_s[t * 16 + lr][ks * 32 + kq];
            acc = MFMA16(a2[ks], b, acc);
        }
        #pragma unroll
        for (int r = 0; r < 4; ++r) o[t][r] = silu_f(acc[r]);
    }
    __syncthreads();
    #pragma unroll
    for (int t = 0; t < 4; ++t)
        #pragma unroll
        for (int r = 0; r < 4; ++r)
            u_s[w * 16 + lq * 4 + r][t * 16 + lr] = f2bf(o[t][r]);
    __syncthreads();

    #pragma unroll
    for (int it = 0; it < 2; ++it) {
        int idx = it * 512 + tid;
        int r = idx >> 3, c8 = (idx & 7) * 8;
        int grow = row0 + r;
        if (grow < E)
            *(uint4*)(x64b + (size_t)grow * ICH + c8) = *(const uint4*)&u_s[r][c8];
    }
}

// ---------------- fully fused tail: combine + res_b0 + lin + res_a0 + res_a1 ----------------
__global__ __launch_bounds__(512) void treslin_k(
    const float* __restrict__ x, const unsigned short* __restrict__ Wt_ji,
    const float* __restrict__ b_ji, const unsigned short* __restrict__ aggB,
    const unsigned short* __restrict__ Wt_up,
    const unsigned short* __restrict__ Wt_rb,   // W0, W1 (+WSEG)
    const unsigned short* __restrict__ Wt_lin,
    const unsigned short* __restrict__ Wt_ra,   // 4 panels
    const float* __restrict__ rbB,              // [2][192]
    const float* __restrict__ b_lin,
    const float* __restrict__ raB,              // [4][192]
    float* __restrict__ out, int E)
{
    __shared__ unsigned short b_s[192][200];   // 76.8 KB
    __shared__ unsigned short t_s[128][200];   // 51.2 KB (wave-private rows)
    __shared__ unsigned short bu_s[192][72];   // 27.6 KB (W_up, P0 only)
    const int tid = threadIdx.x;
    const int lane = tid & 63, w = tid >> 6;
    const int row0 = blockIdx.x * 128;
    const int lr = lane & 15, lq = lane >> 4;
    const int kq = lq * 8;
    const int ra = row0 + w * 16 + lr;
    const bool rav = ra < E;

    STAGE_B(Wt_ji);
    #pragma unroll
    for (int it = 0; it < 3; ++it) {
        int idx = it * 512 + tid;
        int r = idx / 8, c8 = idx % 8;
        *(uint4*)&bu_s[r][c8 * 8] = *(const uint4*)(Wt_up + (size_t)r * ICH + c8 * 8);
    }

    bfrag aag[2], af[6];
    #pragma unroll
    for (int ks = 0; ks < 2; ++ks)
        aag[ks] = rav ? *(const bfrag*)(aggB + (size_t)ra * ICH + ks * 32 + kq) : bzero();
    #pragma unroll
    for (int ks = 0; ks < 6; ++ks) {
        float4 a0 = make_float4(0,0,0,0), a1 = make_float4(0,0,0,0);
        if (rav) {
            a0 = *(const float4*)(x + (size_t)ra * HCH + ks * 32 + kq);
            a1 = *(const float4*)(x + (size_t)ra * HCH + ks * 32 + kq + 4);
        }
        af[ks] = pack8(a0, a1);
    }
    __syncthreads();

    // P0: h = silu(x@W_ji + b_ji) + silu(agg@W_up); fp32 -> hreg, bf16 -> t_s
    float hreg[12][4];
    #pragma unroll
    for (int t = 0; t < 12; ++t) {
        f32x4 au = (f32x4){0.f, 0.f, 0.f, 0.f};
        #pragma unroll
        for (int ks = 0; ks < 2; ++ks) {
            bfrag bu = *(const bfrag*)&bu_s[t * 16 + lr][ks * 32 + kq];
            au = MFMA16(aag[ks], bu, au);
        }
        f32x4 aj = (f32x4){0.f, 0.f, 0.f, 0.f};
        #pragma unroll
        for (int ks = 0; ks < 6; ++ks) {
            bfrag b = *(const bfrag*)&b_s[t * 16 + lr][ks * 32 + kq];
            aj = MFMA16(af[ks], b, aj);
        }
        int col = t * 16 + lr;
        float bb = b_ji[col];
        #pragma unroll
        for (int r = 0; r < 4; ++r) {
            float h = silu_f(aj[r] + bb) + silu_f(au[r]);
            hreg[t][r] = h;
            t_s[w * 16 + lq * 4 + r][col] = f2bf(h);
        }
    }
    __syncthreads();

    // P1: t = silu(h@W0 + b0)
    STAGE_B(Wt_rb);
    AFRAGS(af);
    __syncthreads();
    #pragma unroll
    for (int t = 0; t < 12; ++t) {
        f32x4 acc = (f32x4){0.f, 0.f, 0.f, 0.f};
        #pragma unroll
        for (int ks = 0; ks < 6; ++ks) {
            bfrag b = *(const bfrag*)&b_s[t * 16 + lr][ks * 32 + kq];
            acc = MFMA16(af[ks], b, acc);
        }
        int col = t * 16 + lr;
        float bb = rbB[col];
        #pragma unroll
        for (int r = 0; r < 4; ++r)
            t_s[w * 16 + lq * 4 + r][col] = f2bf(silu_f(acc[r] + bb));
    }
    __syncthreads();

    // P2: h1 = hreg + silu(t@W1 + b1) -> hreg, t_s
    STAGE_B(Wt_rb + WSEG);
    AFRAGS(af);
    __syncthreads();
    #pragma unroll
    for (int t = 0; t < 12; ++t) {
        f32x4 acc = (f32x4){0.f, 0.f, 0.f, 0.f};
        #pragma unroll
        for (int ks = 0; ks < 6; ++ks) {
            bfrag b = *(const bfrag*)&b_s[t * 16 + lr][ks * 32 + kq];
            acc = MFMA16(af[ks], b, acc);
        }
        int col = t * 16 + lr;
        float bb = rbB[HCH + col];
        #pragma unroll
        for (int r = 0; r < 4; ++r) {
            float h1 = hreg[t][r] + silu_f(acc[r] + bb);
            hreg[t][r] = h1;
            t_s[w * 16 + lq * 4 + r][col] = f2bf(h1);
        }
    }
    __syncthreads();

    // P3: h2 = silu(h1@W_lin + b_lin) + x -> hreg, t_s
    STAGE_B(Wt_lin);
    AFRAGS(af);
    __syncthreads();
    #pragma unroll
    for (int t = 0; t < 12; ++t) {
        f32x4 acc = (f32x4){0.f, 0.f, 0.f, 0.f};
        #pragma unroll
        for (int ks = 0; ks < 6; ++ks) {
            bfrag b = *(const bfrag*)&b_s[t * 16 + lr][ks * 32 + kq];
            acc = MFMA16(af[ks], b, acc);
        }
        int col = t * 16 + lr;
        float bb = b_lin[col];
        #pragma unroll
        for (int r = 0; r < 4; ++r) {
            int grow = row0 + w * 16 + lq * 4 + r;
            float xv = (grow < E) ? x[(size_t)grow * HCH + col] : 0.f;
            float h2 = silu_f(acc[r] + bb) + xv;
            hreg[t][r] = h2;
            t_s[w * 16 + lq * 4 + r][col] = f2bf(h2);
        }
    }
    __syncthreads();

    // P4: t = silu(h2@Wra0_0 + raB0)
    STAGE_B(Wt_ra);
    AFRAGS(af);
    __syncthreads();
    #pragma unroll
    for (int t = 0; t < 12; ++t) {
        f32x4 acc = (f32x4){0.f, 0.f, 0.f, 0.f};
        #pragma unroll
        for (int ks = 0; ks < 6; ++ks) {
            bfrag b = *(const bfrag*)&b_s[t * 16 + lr][ks * 32 + kq];
            acc = MFMA16(af[ks], b, acc);
        }
        int col = t * 16 + lr;
        float bb = raB[col];
        #pragma unroll
        for (int r = 0; r < 4; ++r)
            t_s[w * 16 + lq * 4 + r][col] = f2bf(silu_f(acc[r] + bb));
    }
    __syncthreads();

    // P5: h3 = hreg + silu(t@Wra0_1 + raB1) -> hreg, t_s
    STAGE_B(Wt_ra + WSEG);
    AFRAGS(af);
    __syncthreads();
    #pragma unroll
    for (int t = 0; t < 12; ++t) {
        f32x4 acc = (f32x4){0.f, 0.f, 0.f, 0.f};
        #pragma unroll
        for (int ks = 0; ks < 6; ++ks) {
            bfrag b = *(const bfrag*)&b_s[t * 16 + lr][ks * 32 + kq];
            acc = MFMA16(af[ks], b, acc);
        }
        int col = t * 16 + lr;
        float bb = raB[HCH + col];
        #pragma unroll
        for (int r = 0; r < 4; ++r) {
            float h3 = hreg[t][r] + silu_f(acc[r] + bb);
            hreg[t][r] = h3;
            t_s[w * 16 + lq * 4 + r][col] = f2bf(h3);
        }
    }
    __syncthreads();

    // P6: t = silu(h3@Wra1_0 + raB2)
    STAGE_B(Wt_ra + 2 * WSEG);
    AFRAGS(af);
    __syncthreads();
    #pragma unroll
    for (int t = 0; t < 12; ++t) {
        f32x4 acc = (f32x4){0.f, 0.f, 0.f, 0.f};
        #pragma unroll
        for (int ks = 0; ks < 6; ++ks) {
            bfrag b = *(const bfrag*)&b_s[t * 16 + lr][ks * 32 + kq];
            acc = MFMA16(af[ks], b, acc);
        }
        int col = t * 16 + lr;
        float bb = raB[2 * HCH + col];
        #pragma unroll
        for (int r = 0; r < 4; ++r)
            t_s[w * 16 + lq * 4 + r][col] = f2bf(silu_f(acc[r] + bb));
    }
    __syncthreads();

    // P7: out = hreg + silu(t@Wra1_1 + raB3)  (fp32 out)
    STAGE_B(Wt_ra + 3 * WSEG);
    AFRAGS(af);
    __syncthreads();
    #pragma unroll
    for (int t = 0; t < 12; ++t) {
        f32x4 acc = (f32x4){0.f, 0.f, 0.f, 0.f};
        #pragma unroll
        for (int ks = 0; ks < 6; ++ks) {
            bfrag b = *(const bfrag*)&b_s[t * 16 + lr][ks * 32 + kq];
            acc = MFMA16(af[ks], b, acc);
        }
        int col = t * 16 + lr;
        float bb = raB[3 * HCH + col];
        #pragma unroll
        for (int r = 0; r < 4; ++r) {
            int grow = row0 + w * 16 + lq * 4 + r;
            if (grow >= E) continue;
            out[(size_t)grow * HCH + col] = hreg[t][r] + silu_f(acc[r] + bb);
        }
    }
}

// ---------------- CSR pipeline: histogram, scan, fused p-compute + scatter ----------------
__global__ __launch_bounds__(256) void hist_k(const int* __restrict__ idx_ji,
                                              int* __restrict__ counts, int T)
{
    int t = blockIdx.x * 256 + threadIdx.x;
    if (t < T) atomicAdd(&counts[idx_ji[t]], 1);
}

__global__ __launch_bounds__(256) void psum1_k(const int* __restrict__ counts,
                                               int* __restrict__ bsum, int E) {
    __shared__ int s[256];
    int base = blockIdx.x * 1024;
    int tid = threadIdx.x;
    int sum = 0;
    #pragma unroll
    for (int j = 0; j < 4; ++j) { int i = base + j * 256 + tid; if (i < E) sum += counts[i]; }
    s[tid] = sum; __syncthreads();
    for (int off = 128; off > 0; off >>= 1) {
        if (tid < off) s[tid] += s[tid + off];
        __syncthreads();
    }
    if (tid == 0) bsum[blockIdx.x] = s[0];
}

__global__ __launch_bounds__(512) void psum2_k(int* bsum, int G) {
    __shared__ int s[512];
    int tid = threadIdx.x;
    s[tid] = (tid < G) ? bsum[tid] : 0;
    for (int off = 1; off < 512; off <<= 1) {
        __syncthreads();
        int v = (tid >= off) ? s[tid - off] : 0;
        __syncthreads();
        s[tid] += v;
    }
    __syncthreads();
    if (tid < G) bsum[tid] = (tid == 0) ? 0 : s[tid - 1];
}

__global__ __launch_bounds__(256) void psum3_k(const int* __restrict__ counts,
                                               const int* __restrict__ bsum,
                                               int* __restrict__ start, int E) {
    __shared__ int s[256];
    int tid = threadIdx.x;
    int base = blockIdx.x * 1024 + tid * 4;
    int v[4]; int loc = 0;
    #pragma unroll
    for (int j = 0; j < 4; ++j) { v[j] = (base + j < E) ? counts[base + j] : 0; loc += v[j]; }
    s[tid] = loc;
    for (int off = 1; off < 256; off <<= 1) {
        __syncthreads();
        int t2 = (tid >= off) ? s[tid - off] : 0;
        __syncthreads();
        s[tid] += t2;
    }
    __syncthreads();
    int run = bsum[blockIdx.x] + s[tid] - loc;
    #pragma unroll
    for (int j = 0; j < 4; ++j) { if (base + j < E) start[base + j] = run; run += v[j]; }
}

// fill: compute p = sbf@W1 directly and scatter {kj, p} into bucket order
__global__ __launch_bounds__(256) void fill_k(
    const float* __restrict__ sbf, const int* __restrict__ idx_ji,
    const int* __restrict__ idx_kj, const float* __restrict__ w1,
    int* __restrict__ start, int* __restrict__ kjs,
    unsigned short* __restrict__ pSort, int T)
{
    int t = blockIdx.x * 256 + threadIdx.x;
    if (t >= T) return;
    const float* sp = sbf + (size_t)t * SBFD;
    float acc[8];
    #pragma unroll
    for (int b = 0; b < 8; ++b) acc[b] = 0.f;
    #pragma unroll
    for (int r = 0; r < 40; r += 4) {
        float4 v = *(const float4*)(sp + r);
        #pragma unroll
        for (int b = 0; b < 8; ++b)
            acc[b] += v.x * w1[r * 8 + b] + v.y * w1[(r + 1) * 8 + b]
                    + v.z * w1[(r + 2) * 8 + b] + v.w * w1[(r + 3) * 8 + b];
    }
    {
        float2 v = *(const float2*)(sp + 40);
        #pragma unroll
        for (int b = 0; b < 8; ++b)
            acc[b] += v.x * w1[40 * 8 + b] + v.y * w1[41 * 8 + b];
    }
    uint4 pk;
    pk.x = f2bf2(acc[0], acc[1]);
    pk.y = f2bf2(acc[2], acc[3]);
    pk.z = f2bf2(acc[4], acc[5]);
    pk.w = f2bf2(acc[6], acc[7]);

    int pos = atomicAdd(&start[idx_ji[t]], 1);
    kjs[pos] = idx_kj[t];
    *(uint4*)(pSort + (size_t)pos * 8) = pk;
}

// gather: sequential kjs/pSort streams; only x64b row-gather is random (L3-hot)
__global__ __launch_bounds__(256) void gather_k(
    const int* __restrict__ kjs, const unsigned short* __restrict__ pSort,
    const unsigned short* __restrict__ x64b, const int* __restrict__ start,
    const int* __restrict__ counts, const float* __restrict__ w2,
    unsigned short* __restrict__ aggB, int E)
{
    int tid = threadIdx.x;
    int wave = (blockIdx.x * 256 + tid) >> 6;
    int lane = tid & 63;
    if (wave >= E) return;

    float wcol[8];
    #pragma unroll
    for (int b = 0; b < 8; ++b) wcol[b] = w2[b * 64 + lane];

    int n = counts[wave];
    int end = start[wave];
    int i = end - n;

    float acc = 0.f;
    for (; i + 4 <= end; i += 4) {
        int k0 = kjs[i], k1 = kjs[i + 1], k2 = kjs[i + 2], k3 = kjs[i + 3];
        uint4 q0 = *(const uint4*)(pSort + (size_t)i * 8);
        uint4 q1 = *(const uint4*)(pSort + (size_t)(i + 1) * 8);
        uint4 q2 = *(const uint4*)(pSort + (size_t)(i + 2) * 8);
        uint4 q3 = *(const uint4*)(pSort + (size_t)(i + 3) * 8);
        float x0 = bf2f(x64b[(size_t)k0 * ICH + lane]);
        float x1 = bf2f(x64b[(size_t)k1 * ICH + lane]);
        float x2 = bf2f(x64b[(size_t)k2 * ICH + lane]);
        float x3 = bf2f(x64b[(size_t)k3 * ICH + lane]);
        float s0 = lo16(q0.x)*wcol[0] + hi16(q0.x)*wcol[1] + lo16(q0.y)*wcol[2] + hi16(q0.y)*wcol[3]
                 + lo16(q0.z)*wcol[4] + hi16(q0.z)*wcol[5] + lo16(q0.w)*wcol[6] + hi16(q0.w)*wcol[7];
        float s1 = lo16(q1.x)*wcol[0] + hi16(q1.x)*wcol[1] + lo16(q1.y)*wcol[2] + hi16(q1.y)*wcol[3]
                 + lo16(q1.z)*wcol[4] + hi16(q1.z)*wcol[5] + lo16(q1.w)*wcol[6] + hi16(q1.w)*wcol[7];
        float s2 = lo16(q2.x)*wcol[0] + hi16(q2.x)*wcol[1] + lo16(q2.y)*wcol[2] + hi16(q2.y)*wcol[3]
                 + lo16(q2.z)*wcol[4] + hi16(q2.z)*wcol[5] + lo16(q2.w)*wcol[6] + hi16(q2.w)*wcol[7];
        float s3 = lo16(q3.x)*wcol[0] + hi16(q3.x)*wcol[1] + lo16(q3.y)*wcol[2] + hi16(q3.y)*wcol[3]
                 + lo16(q3.z)*wcol[4] + hi16(q3.z)*wcol[5] + lo16(q3.w)*wcol[6] + hi16(q3.w)*wcol[7];
        acc += s0 * x0 + s1 * x1 + s2 * x2 + s3 * x3;
    }
    for (; i < end; ++i) {
        int kj = kjs[i];
        uint4 q = *(const uint4*)(pSort + (size_t)i * 8);
        float xv = bf2f(x64b[(size_t)kj * ICH + lane]);
        float sc = lo16(q.x)*wcol[0] + hi16(q.x)*wcol[1] + lo16(q.y)*wcol[2] + hi16(q.y)*wcol[3]
                 + lo16(q.z)*wcol[4] + hi16(q.z)*wcol[5] + lo16(q.w)*wcol[6] + hi16(q.w)*wcol[7];
        acc += sc * xv;
    }
    aggB[(size_t)wave * ICH + lane] = f2bf(acc);
}

extern "C" void kernel_launch(void* const* d_in, const int* in_sizes, int n_in,
                              void* d_out, int out_size, void* d_ws, size_t ws_size,
                              hipStream_t stream) {
    const float* x      = (const float*)d_in[0];
    const float* rbf    = (const float*)d_in[1];
    const float* sbf    = (const float*)d_in[2];
    const int*   idx_kj = (const int*)d_in[3];
    const int*   idx_ji = (const int*)d_in[4];
    const float* W_rbf1 = (const float*)d_in[5];
    const float* W_rbf2 = (const float*)d_in[6];
    const float* W_sbf1 = (const float*)d_in[7];
    const float* W_sbf2 = (const float*)d_in[8];
    const float* W_kj   = (const float*)d_in[9];
    const float* b_kj   = (const float*)d_in[10];
    const float* W_ji   = (const float*)d_in[11];
    const float* b_ji   = (const float*)d_in[12];
    const float* W_down = (const float*)d_in[13];
    const float* W_up   = (const float*)d_in[14];
    const float* resbW  = (const float*)d_in[15];
    const float* resbB  = (const float*)d_in[16];
    const float* W_lin  = (const float*)d_in[17];
    const float* b_lin  = (const float*)d_in[18];
    const float* resaW  = (const float*)d_in[19];
    const float* resaB  = (const float*)d_in[20];

    const int E = in_sizes[0] / HCH;
    const int T = in_sizes[3];
    float* out = (float*)d_out;

    // ws: wc_rbf f32[1152] | counts[E] | start[E] | bsum[512] | kjs[T] |
    //     pSort u16[T*8] | x64b u16[E*64] | aggB u16[E*64] | Wt u16[WT_TOTAL]
    float* wc_rbf = (float*)d_ws;
    int*   counts = (int*)(wc_rbf + NRAD * HCH);
    int*   start  = counts + E;
    int*   bsum   = start + E;
    int*   kjs    = bsum + 512;
    unsigned short* pSort = (unsigned short*)(kjs + T);
    unsigned short* x64b  = pSort + (size_t)T * 8;
    unsigned short* aggB  = x64b + (size_t)E * ICH;
    unsigned short* Wt    = aggB + (size_t)E * ICH;

    const unsigned short* Wt_kj   = Wt;
    const unsigned short* Wt_ji   = Wt + 1 * WSEG;
    const unsigned short* Wt_lin  = Wt + 2 * WSEG;
    const unsigned short* Wt_rb0  = Wt + 3 * WSEG;   // W0, W1 at +WSEG
    const unsigned short* Wt_ra   = Wt + 5 * WSEG;   // ra0_0, ra0_1, ra1_0, ra1_1
    const unsigned short* Wt_down = Wt + WT_DOWN;
    const unsigned short* Wt_up   = Wt + WT_UP;

    const int gb128 = (E + 127) / 128;
    const int gt = (T + 255) / 256;
    const int gscan = (E + 1023) / 1024;

    wc_k<<<(NRAD * HCH + NT - 1) / NT, NT, 0, stream>>>(W_rbf1, W_rbf2, wc_rbf);
    prep_k<<<(WT_TOTAL + NT - 1) / NT, NT, 0, stream>>>(W_kj, W_ji, W_lin, resbW, resaW,
                                                        W_down, W_up, Wt);

    // CSR build: histogram -> scan -> fused p-compute + scatter
    hipMemsetAsync(counts, 0, (size_t)E * sizeof(int), stream);
    hist_k<<<gt, 256, 0, stream>>>(idx_ji, counts, T);
    psum1_k<<<gscan, 256, 0, stream>>>(counts, bsum, E);
    psum2_k<<<1, 512, 0, stream>>>(bsum, gscan);
    psum3_k<<<gscan, 256, 0, stream>>>(counts, bsum, start, E);
    fill_k<<<gt, 256, 0, stream>>>(sbf, idx_ji, idx_kj, W_sbf1, start, kjs, pSort, T);

    // x -> x64b (bf16), B via LDS
    fused12_k<<<gb128, 512, 0, stream>>>(x, Wt_kj, b_kj, rbf, wc_rbf, Wt_down, x64b, E);
    // aggB = segment_sum(x64b[kjs] * (pSort@W_sbf2))
    gather_k<<<(E + 3) / 4, 256, 0, stream>>>(kjs, pSort, x64b, start, counts, W_sbf2, aggB, E);
    // fully fused tail: combine + res_b0 + lin + res_a0 + res_a1, fp32 out
    treslin_k<<<gb128, 512, 0, stream>>>(x, Wt_ji, b_ji, aggB, Wt_up,
                                         Wt_rb0, Wt_lin, Wt_ra,
                                         resbB, b_lin, resaB, out, E);
}